// Round 1
// baseline (3366.590 us; speedup 1.0000x reference)
//
#include <hip/hip_runtime.h>
#include <hip/hip_bf16.h>

#define NN 100000
#define NE 800000

// ---------------- aggregation (scatter-add atomics) ----------------
__global__ __launch_bounds__(256) void k_agg1(const float* __restrict__ x,
    const int* __restrict__ ei, float* __restrict__ agg, float* __restrict__ cnt)
{
    int idx = blockIdx.x * 256 + threadIdx.x;
    if (idx >= NE * 32) return;
    int e = idx >> 5, k = idx & 31;
    int s = ei[e], d = ei[NE + e];
    atomicAdd(&agg[d * 32 + k], x[s * 32 + k]);
    if (k == 0) atomicAdd(&cnt[d], 1.0f);
}

__global__ __launch_bounds__(256) void k_agg2(const float* __restrict__ h,
    const int* __restrict__ ei, float* __restrict__ agg)
{
    int idx = blockIdx.x * 256 + threadIdx.x;
    if (idx >= NE * 128) return;
    int e = idx >> 7, k = idx & 127;
    int s = ei[e], d = ei[NE + e];
    atomicAdd(&agg[d * 128 + k], h[s * 128 + k]);
}

// ---------------- SAGE layer 1: h1pre = mean(agg)@Wl + x@Wr + b, + bn stats ----------------
__global__ __launch_bounds__(256) void k_node_l1(
    const float* __restrict__ agg, const float* __restrict__ cnt,
    const float* __restrict__ x,
    const float* __restrict__ Wl, const float* __restrict__ Wr,
    const float* __restrict__ bias,
    float* __restrict__ outp, float* __restrict__ ssum, float* __restrict__ ssq)
{
    __shared__ __align__(16) float sWl[32][128];
    __shared__ __align__(16) float sWr[32][128];
    __shared__ __align__(16) float sA[32][36];
    __shared__ __align__(16) float sB[32][36];
    __shared__ float red[2][128], red2[2][128];
    int tid = threadIdx.x;
    int j = tid & 127, rg = tid >> 7;
    int r0 = blockIdx.x * 32;

    for (int f = tid * 4; f < 4096; f += 1024) {
        *(float4*)((float*)sWl + f) = *(const float4*)(Wl + f);
        *(float4*)((float*)sWr + f) = *(const float4*)(Wr + f);
    }
    {
        int r = tid >> 3, c = (tid & 7) * 4;
        float inv = 1.0f / fmaxf(cnt[r0 + r], 1.0f);
        float4 a = *(const float4*)(agg + (r0 + r) * 32 + c);
        sA[r][c] = a.x * inv; sA[r][c+1] = a.y * inv; sA[r][c+2] = a.z * inv; sA[r][c+3] = a.w * inv;
        *(float4*)(&sB[r][c]) = *(const float4*)(x + (r0 + r) * 32 + c);
    }
    __syncthreads();

    float acc[16];
    #pragma unroll
    for (int r = 0; r < 16; r++) acc[r] = 0.0f;
    int rb = rg * 16;
    #pragma unroll
    for (int kq = 0; kq < 8; kq++) {
        int k = kq * 4;
        float wl0 = sWl[k][j], wl1 = sWl[k+1][j], wl2 = sWl[k+2][j], wl3 = sWl[k+3][j];
        float wr0 = sWr[k][j], wr1 = sWr[k+1][j], wr2 = sWr[k+2][j], wr3 = sWr[k+3][j];
        #pragma unroll
        for (int r = 0; r < 16; r++) {
            float4 a = *(float4*)(&sA[rb + r][k]);
            float4 b = *(float4*)(&sB[rb + r][k]);
            acc[r] += a.x*wl0 + a.y*wl1 + a.z*wl2 + a.w*wl3
                    + b.x*wr0 + b.y*wr1 + b.z*wr2 + b.w*wr3;
        }
    }
    float bj = bias[j];
    float s1 = 0.0f, s2 = 0.0f;
    #pragma unroll
    for (int r = 0; r < 16; r++) {
        float v = acc[r] + bj;
        outp[(r0 + rb + r) * 128 + j] = v;
        s1 += v; s2 += v * v;
    }
    red[rg][j] = s1; red2[rg][j] = s2;
    __syncthreads();
    if (rg == 0) {
        atomicAdd(&ssum[j], red[0][j] + red[1][j]);
        atomicAdd(&ssq[j],  red2[0][j] + red2[1][j]);
    }
}

// ---------------- SAGE layer 2 (K=128 dual GEMM + bn stats) ----------------
__global__ __launch_bounds__(256) void k_node_l2(
    const float* __restrict__ agg, const float* __restrict__ cnt,
    const float* __restrict__ h1,
    const float* __restrict__ Wl, const float* __restrict__ Wr,
    const float* __restrict__ bias,
    float* __restrict__ outp, float* __restrict__ ssum, float* __restrict__ ssq)
{
    __shared__ __align__(16) float sWl[32][128];
    __shared__ __align__(16) float sWr[32][128];
    __shared__ __align__(16) float sA[16][132];
    __shared__ __align__(16) float sB[16][132];
    __shared__ float red[2][128], red2[2][128];
    int tid = threadIdx.x;
    int j = tid & 127, rg = tid >> 7;
    int r0 = blockIdx.x * 16;
    {
        int r = tid >> 4, c = (tid & 15) * 8;
        float inv = 1.0f / fmaxf(cnt[r0 + r], 1.0f);
        float4 a0 = *(const float4*)(agg + (r0 + r) * 128 + c);
        float4 a1 = *(const float4*)(agg + (r0 + r) * 128 + c + 4);
        sA[r][c]  =a0.x*inv; sA[r][c+1]=a0.y*inv; sA[r][c+2]=a0.z*inv; sA[r][c+3]=a0.w*inv;
        sA[r][c+4]=a1.x*inv; sA[r][c+5]=a1.y*inv; sA[r][c+6]=a1.z*inv; sA[r][c+7]=a1.w*inv;
        *(float4*)(&sB[r][c])   = *(const float4*)(h1 + (r0 + r) * 128 + c);
        *(float4*)(&sB[r][c+4]) = *(const float4*)(h1 + (r0 + r) * 128 + c + 4);
    }
    float acc[8];
    #pragma unroll
    for (int r = 0; r < 8; r++) acc[r] = 0.0f;
    int rb = rg * 8;
    for (int kc = 0; kc < 4; kc++) {
        __syncthreads();
        for (int f = tid * 4; f < 4096; f += 1024) {
            *(float4*)((float*)sWl + f) = *(const float4*)(Wl + kc * 4096 + f);
            *(float4*)((float*)sWr + f) = *(const float4*)(Wr + kc * 4096 + f);
        }
        __syncthreads();
        #pragma unroll
        for (int kq = 0; kq < 8; kq++) {
            int k = kq * 4, kg = kc * 32 + k;
            float wl0=sWl[k][j],wl1=sWl[k+1][j],wl2=sWl[k+2][j],wl3=sWl[k+3][j];
            float wr0=sWr[k][j],wr1=sWr[k+1][j],wr2=sWr[k+2][j],wr3=sWr[k+3][j];
            #pragma unroll
            for (int r = 0; r < 8; r++) {
                float4 a = *(float4*)(&sA[rb + r][kg]);
                float4 b = *(float4*)(&sB[rb + r][kg]);
                acc[r] += a.x*wl0+a.y*wl1+a.z*wl2+a.w*wl3
                        + b.x*wr0+b.y*wr1+b.z*wr2+b.w*wr3;
            }
        }
    }
    float bj = bias[j];
    float s1 = 0, s2 = 0;
    #pragma unroll
    for (int r = 0; r < 8; r++) {
        float v = acc[r] + bj;
        outp[(r0 + rb + r) * 128 + j] = v;
        s1 += v; s2 += v * v;
    }
    red[rg][j]=s1; red2[rg][j]=s2;
    __syncthreads();
    if (rg == 0) {
        atomicAdd(&ssum[j], red[0][j]+red[1][j]);
        atomicAdd(&ssq[j],  red2[0][j]+red2[1][j]);
    }
}

// ---------------- plain C = A @ W  (N x 128 @ 128 x 128), for hs/hd ----------------
__global__ __launch_bounds__(256) void k_proj(
    const float* __restrict__ A, const float* __restrict__ W, float* __restrict__ C)
{
    __shared__ __align__(16) float sW[32][128];
    __shared__ __align__(16) float sA[32][132];
    int tid = threadIdx.x;
    int j = tid & 127, rg = tid >> 7;
    int r0 = blockIdx.x * 32;
    {
        int r = tid >> 3, c = (tid & 7) * 16;
        #pragma unroll
        for (int q = 0; q < 4; q++)
            *(float4*)(&sA[r][c + q*4]) = *(const float4*)(A + (r0 + r) * 128 + c + q*4);
    }
    float acc[16];
    #pragma unroll
    for (int r = 0; r < 16; r++) acc[r] = 0.0f;
    int rb = rg * 16;
    for (int kc = 0; kc < 4; kc++) {
        __syncthreads();
        for (int f = tid * 4; f < 4096; f += 1024)
            *(float4*)((float*)sW + f) = *(const float4*)(W + kc * 4096 + f);
        __syncthreads();
        #pragma unroll
        for (int kq = 0; kq < 8; kq++) {
            int k = kq * 4, kg = kc * 32 + k;
            float w0=sW[k][j],w1=sW[k+1][j],w2=sW[k+2][j],w3=sW[k+3][j];
            #pragma unroll
            for (int r = 0; r < 16; r++) {
                float4 a = *(float4*)(&sA[rb + r][kg]);
                acc[r] += a.x*w0+a.y*w1+a.z*w2+a.w*w3;
            }
        }
    }
    #pragma unroll
    for (int r = 0; r < 16; r++)
        C[(r0 + rb + r) * 128 + j] = acc[r];
}

// ---------------- batch-norm finalize + apply ----------------
__global__ void k_bn_fin(const float* __restrict__ ssum, const float* __restrict__ ssq,
    const float* __restrict__ g, const float* __restrict__ b, float count,
    float* __restrict__ scale, float* __restrict__ shift)
{
    int j = threadIdx.x;
    float m = ssum[j] / count;
    float var = ssq[j] / count - m * m;
    float rs = rsqrtf(var + 1e-5f);
    float sc = g[j] * rs;
    scale[j] = sc;
    shift[j] = b[j] - m * sc;
}

__global__ __launch_bounds__(256) void k_bnrelu(float* __restrict__ h,
    const float* __restrict__ scale, const float* __restrict__ shift)
{
    int idx = blockIdx.x * 256 + threadIdx.x;   // per float4, exact grid
    int base = idx * 4;
    int j = base & 127;
    float4 v = *(float4*)(h + base);
    v.x = fmaxf(v.x * scale[j]   + shift[j],   0.0f);
    v.y = fmaxf(v.y * scale[j+1] + shift[j+1], 0.0f);
    v.z = fmaxf(v.z * scale[j+2] + shift[j+2], 0.0f);
    v.w = fmaxf(v.w * scale[j+3] + shift[j+3], 0.0f);
    *(float4*)(h + base) = v;
}

// ---------------- edge pass 1: stats of t = relu(ea@We + be) ----------------
__global__ __launch_bounds__(256) void k_edge_stats(
    const float* __restrict__ ea, const float* __restrict__ We, const float* __restrict__ be,
    float* __restrict__ ssum, float* __restrict__ ssq)
{
    __shared__ __align__(16) float sWe[16][128];
    __shared__ float red[2][128], red2[2][128];
    int tid = threadIdx.x, j = tid & 127, rg = tid >> 7;
    for (int f = tid * 4; f < 2048; f += 1024)
        *(float4*)((float*)sWe + f) = *(const float4*)(We + f);
    __syncthreads();
    float bj = be[j];
    float s1 = 0, s2 = 0;
    for (int t = blockIdx.x; t < NE / 32; t += gridDim.x) {
        int e0 = t * 32 + rg * 16;
        for (int r = 0; r < 16; r++) {
            const float4* row = (const float4*)(ea + (e0 + r) * 16);
            float av[16];
            *(float4*)(av)=row[0]; *(float4*)(av+4)=row[1];
            *(float4*)(av+8)=row[2]; *(float4*)(av+12)=row[3];
            float v = bj;
            #pragma unroll
            for (int kk = 0; kk < 16; kk++) v += av[kk] * sWe[kk][j];
            v = fmaxf(v, 0.0f);
            s1 += v; s2 += v * v;
        }
    }
    red[rg][j]=s1; red2[rg][j]=s2;
    __syncthreads();
    if (rg == 0) {
        atomicAdd(&ssum[j], red[0][j]+red[1][j]);
        atomicAdd(&ssq[j],  red2[0][j]+red2[1][j]);
    }
}

// ---------------- fold bne affine into Wm1[256:384] ----------------
__global__ void k_fold_e(const float* __restrict__ ssum, const float* __restrict__ ssq,
    const float* __restrict__ g, const float* __restrict__ b,
    const float* __restrict__ Wm1, const float* __restrict__ bm1,
    float* __restrict__ W1p, float* __restrict__ bm1p)
{
    __shared__ float sa[128], sc[128];
    int tid = threadIdx.x;
    float m = ssum[tid] / (float)NE;
    float var = ssq[tid] / (float)NE - m * m;
    float rs = rsqrtf(var + 1e-5f);
    float a = g[tid] * rs;
    sa[tid] = a; sc[tid] = b[tid] - m * a;
    __syncthreads();
    float acc = bm1[tid];
    for (int k = 0; k < 128; k++) {
        float w = Wm1[(256 + k) * 128 + tid];
        W1p[k * 128 + tid] = sa[k] * w;
        acc += sc[k] * w;
    }
    bm1p[tid] = acc;
}

// ---------------- fold bnm affine into Wm2 ----------------
__global__ void k_fold_m(const float* __restrict__ ssum, const float* __restrict__ ssq,
    const float* __restrict__ g, const float* __restrict__ b,
    const float* __restrict__ Wm2, const float* __restrict__ bm2,
    float* __restrict__ W2p, float* __restrict__ b2p)
{
    __shared__ float sa[128], sc[128];
    int tid = threadIdx.x;
    float m = ssum[tid] / (float)NE;
    float var = ssq[tid] / (float)NE - m * m;
    float rs = rsqrtf(var + 1e-5f);
    float a = g[tid] * rs;
    sa[tid] = a; sc[tid] = b[tid] - m * a;
    __syncthreads();
    if (tid < 64) {
        int q = tid;
        float acc = bm2[q];
        for (int k = 0; k < 128; k++) {
            float w = Wm2[k * 64 + q];
            W2p[k * 64 + q] = sa[k] * w;
            acc += sc[k] * w;
        }
        b2p[q] = acc;
    }
}

// ---------------- edge pass 2: v = relu(t@W1p + bm1p + hs[es] + hd[et]); bnm stats ----------------
template<bool STORE_V>
__global__ __launch_bounds__(256) void k_edge_main(
    const float* __restrict__ ea, const float* __restrict__ We, const float* __restrict__ be,
    const float* __restrict__ W1p, const float* __restrict__ bm1p,
    const float* __restrict__ hs, const float* __restrict__ hd,
    const int* __restrict__ esrc, const int* __restrict__ etgt,
    float* __restrict__ ssum, float* __restrict__ ssq,
    __hip_bfloat16* __restrict__ vout)
{
    __shared__ __align__(16) float sWe[16][128];
    __shared__ __align__(16) float sT[32][132];
    __shared__ __align__(16) float sW[32][128];
    __shared__ float red[2][128], red2[2][128];
    int tid = threadIdx.x, j = tid & 127, rg = tid >> 7;
    for (int f = tid * 4; f < 2048; f += 1024)
        *(float4*)((float*)sWe + f) = *(const float4*)(We + f);
    float bj = be[j], bmj = bm1p[j];
    float s1 = 0, s2 = 0;
    int rb = rg * 16;
    for (int t = blockIdx.x; t < NE / 32; t += gridDim.x) {
        int e0 = t * 32;
        __syncthreads();
        for (int r = 0; r < 16; r++) {
            const float4* row = (const float4*)(ea + (e0 + rb + r) * 16);
            float av[16];
            *(float4*)(av)=row[0]; *(float4*)(av+4)=row[1];
            *(float4*)(av+8)=row[2]; *(float4*)(av+12)=row[3];
            float v = bj;
            #pragma unroll
            for (int kk = 0; kk < 16; kk++) v += av[kk] * sWe[kk][j];
            sT[rb + r][j] = fmaxf(v, 0.0f);
        }
        float acc[16];
        #pragma unroll
        for (int r = 0; r < 16; r++) acc[r] = bmj;
        for (int kc = 0; kc < 4; kc++) {
            __syncthreads();
            for (int f = tid * 4; f < 4096; f += 1024)
                *(float4*)((float*)sW + f) = *(const float4*)(W1p + kc * 4096 + f);
            __syncthreads();
            #pragma unroll
            for (int kq = 0; kq < 8; kq++) {
                int k = kq * 4, kg = kc * 32 + k;
                float w0=sW[k][j],w1=sW[k+1][j],w2=sW[k+2][j],w3=sW[k+3][j];
                #pragma unroll
                for (int r = 0; r < 16; r++) {
                    float4 a = *(float4*)(&sT[rb + r][kg]);
                    acc[r] += a.x*w0+a.y*w1+a.z*w2+a.w*w3;
                }
            }
        }
        for (int r = 0; r < 16; r++) {
            int e = e0 + rb + r;
            int is = esrc[e], it = etgt[e];
            float v = acc[r] + hs[is * 128 + j] + hd[it * 128 + j];
            v = fmaxf(v, 0.0f);
            s1 += v; s2 += v * v;
            if constexpr (STORE_V) vout[(size_t)e * 128 + j] = __float2bfloat16(v);
        }
    }
    red[rg][j]=s1; red2[rg][j]=s2;
    __syncthreads();
    if (rg == 0) {
        atomicAdd(&ssum[j], red[0][j]+red[1][j]);
        atomicAdd(&ssq[j],  red2[0][j]+red2[1][j]);
    }
}

// ---------------- edge pass 3: z2 = relu(v@W2p + b2p); out = z2@Wm3 + bm3 ----------------
template<bool LOAD_V>
__global__ __launch_bounds__(256) void k_edge_final(
    const float* __restrict__ ea, const float* __restrict__ We, const float* __restrict__ be,
    const float* __restrict__ W1p, const float* __restrict__ bm1p,
    const float* __restrict__ hs, const float* __restrict__ hd,
    const int* __restrict__ esrc, const int* __restrict__ etgt,
    const __hip_bfloat16* __restrict__ vin,
    const float* __restrict__ W2p, const float* __restrict__ b2p,
    const float* __restrict__ Wm3, const float* __restrict__ bm3,
    float* __restrict__ outp)
{
    __shared__ __align__(16) float sWe[16][128];
    __shared__ __align__(16) float sT[32][132];
    __shared__ __align__(16) float sW[32][128];   // reused as [64][64] for W2p chunks
    __shared__ __align__(16) float sZ[32][68];
    __shared__ float sW3[64];
    int tid = threadIdx.x, j = tid & 127, rg = tid >> 7;
    if constexpr (!LOAD_V) {
        for (int f = tid * 4; f < 2048; f += 1024)
            *(float4*)((float*)sWe + f) = *(const float4*)(We + f);
    }
    if (tid < 64) sW3[tid] = Wm3[tid];
    float bj = be[j], bmj = bm1p[j];
    int q = tid & 63, rg4 = tid >> 6;
    float b2q = b2p[q];
    float bm3v = bm3[0];
    int rb = rg * 16, rb4 = rg4 * 8;
    for (int t = blockIdx.x; t < NE / 32; t += gridDim.x) {
        int e0 = t * 32;
        __syncthreads();
        if constexpr (LOAD_V) {
            for (int r = 0; r < 16; r++)
                sT[rb + r][j] = __bfloat162float(vin[(size_t)(e0 + rb + r) * 128 + j]);
        } else {
            for (int r = 0; r < 16; r++) {
                const float4* row = (const float4*)(ea + (e0 + rb + r) * 16);
                float av[16];
                *(float4*)(av)=row[0]; *(float4*)(av+4)=row[1];
                *(float4*)(av+8)=row[2]; *(float4*)(av+12)=row[3];
                float v = bj;
                #pragma unroll
                for (int kk = 0; kk < 16; kk++) v += av[kk] * sWe[kk][j];
                sT[rb + r][j] = fmaxf(v, 0.0f);
            }
            float acc[16];
            #pragma unroll
            for (int r = 0; r < 16; r++) acc[r] = bmj;
            for (int kc = 0; kc < 4; kc++) {
                __syncthreads();
                for (int f = tid * 4; f < 4096; f += 1024)
                    *(float4*)((float*)sW + f) = *(const float4*)(W1p + kc * 4096 + f);
                __syncthreads();
                #pragma unroll
                for (int kq = 0; kq < 8; kq++) {
                    int k = kq * 4, kg = kc * 32 + k;
                    float w0=sW[k][j],w1=sW[k+1][j],w2=sW[k+2][j],w3=sW[k+3][j];
                    #pragma unroll
                    for (int r = 0; r < 16; r++) {
                        float4 a = *(float4*)(&sT[rb + r][kg]);
                        acc[r] += a.x*w0+a.y*w1+a.z*w2+a.w*w3;
                    }
                }
            }
            __syncthreads();   // all sT reads done before overwriting with v
            for (int r = 0; r < 16; r++) {
                int e = e0 + rb + r;
                int is = esrc[e], it = etgt[e];
                float v = acc[r] + hs[is * 128 + j] + hd[it * 128 + j];
                sT[rb + r][j] = fmaxf(v, 0.0f);
            }
        }
        __syncthreads();
        float acc2[8];
        #pragma unroll
        for (int r = 0; r < 8; r++) acc2[r] = b2q;
        for (int kc = 0; kc < 2; kc++) {
            __syncthreads();
            for (int f = tid * 4; f < 4096; f += 1024)
                *(float4*)((float*)sW + f) = *(const float4*)(W2p + kc * 4096 + f);
            __syncthreads();
            #pragma unroll
            for (int kq = 0; kq < 16; kq++) {
                int k = kq * 4, kg = kc * 64 + k;
                const float* wf = (const float*)sW;
                float w0=wf[k*64+q], w1=wf[(k+1)*64+q], w2=wf[(k+2)*64+q], w3=wf[(k+3)*64+q];
                #pragma unroll
                for (int r = 0; r < 8; r++) {
                    float4 a = *(float4*)(&sT[rb4 + r][kg]);
                    acc2[r] += a.x*w0+a.y*w1+a.z*w2+a.w*w3;
                }
            }
        }
        #pragma unroll
        for (int r = 0; r < 8; r++) sZ[rb4 + r][q] = fmaxf(acc2[r], 0.0f);
        __syncthreads();
        if (tid < 32) {
            float o = bm3v;
            #pragma unroll 8
            for (int k2 = 0; k2 < 64; k2++) o += sZ[tid][k2] * sW3[k2];
            outp[e0 + tid] = o;
        }
    }
}

extern "C" void kernel_launch(void* const* d_in, const int* in_sizes, int n_in,
                              void* d_out, int out_size, void* d_ws, size_t ws_size,
                              hipStream_t stream) {
    const float* x     = (const float*)d_in[0];
    const int*   ei    = (const int*)  d_in[1];
    const float* eattr = (const float*)d_in[2];
    const int*   esrc  = (const int*)  d_in[3];
    const int*   etgt  = (const int*)  d_in[4];
    const float* W1l = (const float*)d_in[5];  const float* b1 = (const float*)d_in[6];
    const float* W1r = (const float*)d_in[7];
    const float* W2l = (const float*)d_in[8];  const float* b2 = (const float*)d_in[9];
    const float* W2r = (const float*)d_in[10];
    const float* bn1_g = (const float*)d_in[11]; const float* bn1_b = (const float*)d_in[12];
    const float* bn2_g = (const float*)d_in[13]; const float* bn2_b = (const float*)d_in[14];
    const float* We  = (const float*)d_in[15]; const float* be  = (const float*)d_in[16];
    const float* bne_g = (const float*)d_in[17]; const float* bne_b = (const float*)d_in[18];
    const float* Wm1 = (const float*)d_in[19]; const float* bm1 = (const float*)d_in[20];
    const float* bnm_g = (const float*)d_in[21]; const float* bnm_b = (const float*)d_in[22];
    const float* Wm2 = (const float*)d_in[23]; const float* bm2 = (const float*)d_in[24];
    const float* Wm3 = (const float*)d_in[25]; const float* bm3 = (const float*)d_in[26];
    float* out = (float*)d_out;

    float* ws = (float*)d_ws;
    size_t off = 0;
    float* S0  = ws + off; off += (size_t)NN * 128;   // agg1/agg2 -> later hs
    float* S1  = ws + off; off += (size_t)NN * 128;   // h1 -> later hd
    float* S2  = ws + off; off += (size_t)NN * 128;   // h2
    float* cnt = ws + off; off += NN;
    float* st  = ws + off; off += 1024;               // 8 x 128 stat accumulators
    float* sc1 = ws + off; off += 128;  float* sh1 = ws + off; off += 128;
    float* sc2 = ws + off; off += 128;  float* sh2 = ws + off; off += 128;
    float* W1p = ws + off; off += 128 * 128;
    float* bm1p= ws + off; off += 128;
    float* W2p = ws + off; off += 128 * 64;
    float* b2p = ws + off; off += 64;
    __hip_bfloat16* vbuf = (__hip_bfloat16*)(ws + off);
    size_t need_v = off * 4 + (size_t)NE * 128 * 2;
    bool store_v = (ws_size >= need_v);

    hipMemsetAsync(S0, 0, (size_t)NN * 32 * 4, stream);   // layer-1 agg region [N][32]
    hipMemsetAsync(cnt, 0, (size_t)NN * 4, stream);
    hipMemsetAsync(st, 0, 1024 * 4, stream);

    // ---- layer 1 ----
    k_agg1<<<(NE * 32) / 256, 256, 0, stream>>>(x, ei, S0, cnt);
    k_node_l1<<<NN / 32, 256, 0, stream>>>(S0, cnt, x, W1l, W1r, b1, S1, st + 0, st + 128);
    k_bn_fin<<<1, 128, 0, stream>>>(st + 0, st + 128, bn1_g, bn1_b, (float)NN, sc1, sh1);
    k_bnrelu<<<(NN * 128 / 4) / 256, 256, 0, stream>>>(S1, sc1, sh1);

    // ---- layer 2 ----
    hipMemsetAsync(S0, 0, (size_t)NN * 128 * 4, stream);
    k_agg2<<<(NE * 128) / 256, 256, 0, stream>>>(S1, ei, S0);
    k_node_l2<<<NN / 16, 256, 0, stream>>>(S0, cnt, S1, W2l, W2r, b2, S2, st + 256, st + 384);
    k_bn_fin<<<1, 128, 0, stream>>>(st + 256, st + 384, bn2_g, bn2_b, (float)NN, sc2, sh2);
    k_bnrelu<<<(NN * 128 / 4) / 256, 256, 0, stream>>>(S2, sc2, sh2);

    // ---- node projections for the edge MLP (hs -> S0, hd -> S1) ----
    k_proj<<<NN / 32, 256, 0, stream>>>(S2, Wm1, S0);
    k_proj<<<NN / 32, 256, 0, stream>>>(S2, Wm1 + 128 * 128, S1);

    // ---- edge pipeline ----
    k_edge_stats<<<2048, 256, 0, stream>>>(eattr, We, be, st + 512, st + 640);
    k_fold_e<<<1, 128, 0, stream>>>(st + 512, st + 640, bne_g, bne_b, Wm1, bm1, W1p, bm1p);
    if (store_v)
        k_edge_main<true><<<2048, 256, 0, stream>>>(eattr, We, be, W1p, bm1p, S0, S1,
                                                    esrc, etgt, st + 768, st + 896, vbuf);
    else
        k_edge_main<false><<<2048, 256, 0, stream>>>(eattr, We, be, W1p, bm1p, S0, S1,
                                                     esrc, etgt, st + 768, st + 896, (__hip_bfloat16*)nullptr);
    k_fold_m<<<1, 128, 0, stream>>>(st + 768, st + 896, bnm_g, bnm_b, Wm2, bm2, W2p, b2p);
    if (store_v)
        k_edge_final<true><<<2048, 256, 0, stream>>>(eattr, We, be, W1p, bm1p, S0, S1,
                                                     esrc, etgt, vbuf, W2p, b2p, Wm3, bm3, out);
    else
        k_edge_final<false><<<2048, 256, 0, stream>>>(eattr, We, be, W1p, bm1p, S0, S1,
                                                      esrc, etgt, (const __hip_bfloat16*)nullptr,
                                                      W2p, b2p, Wm3, bm3, out);
}

// Round 2
// 1634.707 us; speedup vs baseline: 2.0594x; 2.0594x over previous
//
#include <hip/hip_runtime.h>
#include <hip/hip_bf16.h>

#define NN 100000
#define NE 800000

typedef __attribute__((ext_vector_type(8))) short bf16x8;
typedef __attribute__((ext_vector_type(4))) float f32x4;

// fp32 -> bf16 (round-to-nearest-even), bit pattern as short
__device__ __forceinline__ short f2b(float f) {
    unsigned u = __float_as_uint(f);
    unsigned r = (u + 0x7fffu + ((u >> 16) & 1u)) >> 16;
    return (short)r;
}

// ---------------- aggregation (scatter-add atomics) ----------------
__global__ __launch_bounds__(256) void k_agg1(const float* __restrict__ x,
    const int* __restrict__ ei, float* __restrict__ agg, float* __restrict__ cnt)
{
    int idx = blockIdx.x * 256 + threadIdx.x;
    if (idx >= NE * 32) return;
    int e = idx >> 5, k = idx & 31;
    int s = ei[e], d = ei[NE + e];
    atomicAdd(&agg[d * 32 + k], x[s * 32 + k]);
    if (k == 0) atomicAdd(&cnt[d], 1.0f);
}

__global__ __launch_bounds__(256) void k_agg2(const float* __restrict__ h,
    const int* __restrict__ ei, float* __restrict__ agg)
{
    int idx = blockIdx.x * 256 + threadIdx.x;
    if (idx >= NE * 128) return;
    int e = idx >> 7, k = idx & 127;
    int s = ei[e], d = ei[NE + e];
    atomicAdd(&agg[d * 128 + k], h[s * 128 + k]);
}

// ---------------- SAGE layer 1 (fp32, K=16+16) ----------------
__global__ __launch_bounds__(256) void k_node_l1(
    const float* __restrict__ agg, const float* __restrict__ cnt,
    const float* __restrict__ x,
    const float* __restrict__ Wl, const float* __restrict__ Wr,
    const float* __restrict__ bias,
    float* __restrict__ outp, float* __restrict__ ssum, float* __restrict__ ssq)
{
    __shared__ __align__(16) float sWl[32][128];
    __shared__ __align__(16) float sWr[32][128];
    __shared__ __align__(16) float sA[32][36];
    __shared__ __align__(16) float sB[32][36];
    __shared__ float red[2][128], red2[2][128];
    int tid = threadIdx.x;
    int j = tid & 127, rg = tid >> 7;
    int r0 = blockIdx.x * 32;

    for (int f = tid * 4; f < 4096; f += 1024) {
        *(float4*)((float*)sWl + f) = *(const float4*)(Wl + f);
        *(float4*)((float*)sWr + f) = *(const float4*)(Wr + f);
    }
    {
        int r = tid >> 3, c = (tid & 7) * 4;
        float inv = 1.0f / fmaxf(cnt[r0 + r], 1.0f);
        float4 a = *(const float4*)(agg + (r0 + r) * 32 + c);
        sA[r][c] = a.x * inv; sA[r][c+1] = a.y * inv; sA[r][c+2] = a.z * inv; sA[r][c+3] = a.w * inv;
        *(float4*)(&sB[r][c]) = *(const float4*)(x + (r0 + r) * 32 + c);
    }
    __syncthreads();

    float acc[16];
    #pragma unroll
    for (int r = 0; r < 16; r++) acc[r] = 0.0f;
    int rb = rg * 16;
    #pragma unroll
    for (int kq = 0; kq < 8; kq++) {
        int k = kq * 4;
        float wl0 = sWl[k][j], wl1 = sWl[k+1][j], wl2 = sWl[k+2][j], wl3 = sWl[k+3][j];
        float wr0 = sWr[k][j], wr1 = sWr[k+1][j], wr2 = sWr[k+2][j], wr3 = sWr[k+3][j];
        #pragma unroll
        for (int r = 0; r < 16; r++) {
            float4 a = *(float4*)(&sA[rb + r][k]);
            float4 b = *(float4*)(&sB[rb + r][k]);
            acc[r] += a.x*wl0 + a.y*wl1 + a.z*wl2 + a.w*wl3
                    + b.x*wr0 + b.y*wr1 + b.z*wr2 + b.w*wr3;
        }
    }
    float bj = bias[j];
    float s1 = 0.0f, s2 = 0.0f;
    #pragma unroll
    for (int r = 0; r < 16; r++) {
        float v = acc[r] + bj;
        outp[(r0 + rb + r) * 128 + j] = v;
        s1 += v; s2 += v * v;
    }
    red[rg][j] = s1; red2[rg][j] = s2;
    __syncthreads();
    if (rg == 0) {
        atomicAdd(&ssum[j], red[0][j] + red[1][j]);
        atomicAdd(&ssq[j],  red2[0][j] + red2[1][j]);
    }
}

// ---------------- SAGE layer 2 (fp32 dual K=128) ----------------
__global__ __launch_bounds__(256) void k_node_l2(
    const float* __restrict__ agg, const float* __restrict__ cnt,
    const float* __restrict__ h1,
    const float* __restrict__ Wl, const float* __restrict__ Wr,
    const float* __restrict__ bias,
    float* __restrict__ outp, float* __restrict__ ssum, float* __restrict__ ssq)
{
    __shared__ __align__(16) float sWl[32][128];
    __shared__ __align__(16) float sWr[32][128];
    __shared__ __align__(16) float sA[16][132];
    __shared__ __align__(16) float sB[16][132];
    __shared__ float red[2][128], red2[2][128];
    int tid = threadIdx.x;
    int j = tid & 127, rg = tid >> 7;
    int r0 = blockIdx.x * 16;
    {
        int r = tid >> 4, c = (tid & 15) * 8;
        float inv = 1.0f / fmaxf(cnt[r0 + r], 1.0f);
        float4 a0 = *(const float4*)(agg + (r0 + r) * 128 + c);
        float4 a1 = *(const float4*)(agg + (r0 + r) * 128 + c + 4);
        sA[r][c]  =a0.x*inv; sA[r][c+1]=a0.y*inv; sA[r][c+2]=a0.z*inv; sA[r][c+3]=a0.w*inv;
        sA[r][c+4]=a1.x*inv; sA[r][c+5]=a1.y*inv; sA[r][c+6]=a1.z*inv; sA[r][c+7]=a1.w*inv;
        *(float4*)(&sB[r][c])   = *(const float4*)(h1 + (r0 + r) * 128 + c);
        *(float4*)(&sB[r][c+4]) = *(const float4*)(h1 + (r0 + r) * 128 + c + 4);
    }
    float acc[8];
    #pragma unroll
    for (int r = 0; r < 8; r++) acc[r] = 0.0f;
    int rb = rg * 8;
    for (int kc = 0; kc < 4; kc++) {
        __syncthreads();
        for (int f = tid * 4; f < 4096; f += 1024) {
            *(float4*)((float*)sWl + f) = *(const float4*)(Wl + kc * 4096 + f);
            *(float4*)((float*)sWr + f) = *(const float4*)(Wr + kc * 4096 + f);
        }
        __syncthreads();
        #pragma unroll
        for (int kq = 0; kq < 8; kq++) {
            int k = kq * 4, kg = kc * 32 + k;
            float wl0=sWl[k][j],wl1=sWl[k+1][j],wl2=sWl[k+2][j],wl3=sWl[k+3][j];
            float wr0=sWr[k][j],wr1=sWr[k+1][j],wr2=sWr[k+2][j],wr3=sWr[k+3][j];
            #pragma unroll
            for (int r = 0; r < 8; r++) {
                float4 a = *(float4*)(&sA[rb + r][kg]);
                float4 b = *(float4*)(&sB[rb + r][kg]);
                acc[r] += a.x*wl0+a.y*wl1+a.z*wl2+a.w*wl3
                        + b.x*wr0+b.y*wr1+b.z*wr2+b.w*wr3;
            }
        }
    }
    float bj = bias[j];
    float s1 = 0, s2 = 0;
    #pragma unroll
    for (int r = 0; r < 8; r++) {
        float v = acc[r] + bj;
        outp[(r0 + rb + r) * 128 + j] = v;
        s1 += v; s2 += v * v;
    }
    red[rg][j]=s1; red2[rg][j]=s2;
    __syncthreads();
    if (rg == 0) {
        atomicAdd(&ssum[j], red[0][j]+red[1][j]);
        atomicAdd(&ssq[j],  red2[0][j]+red2[1][j]);
    }
}

// ---------------- batch-norm finalize + apply ----------------
__global__ void k_bn_fin(const float* __restrict__ ssum, const float* __restrict__ ssq,
    const float* __restrict__ g, const float* __restrict__ b, float count,
    float* __restrict__ scale, float* __restrict__ shift)
{
    int j = threadIdx.x;
    float m = ssum[j] / count;
    float var = ssq[j] / count - m * m;
    float rs = rsqrtf(var + 1e-5f);
    float sc = g[j] * rs;
    scale[j] = sc;
    shift[j] = b[j] - m * sc;
}

__global__ __launch_bounds__(256) void k_bnrelu(float* __restrict__ h,
    const float* __restrict__ scale, const float* __restrict__ shift)
{
    int idx = blockIdx.x * 256 + threadIdx.x;
    int base = idx * 4;
    int j = base & 127;
    float4 v = *(float4*)(h + base);
    v.x = fmaxf(v.x * scale[j]   + shift[j],   0.0f);
    v.y = fmaxf(v.y * scale[j+1] + shift[j+1], 0.0f);
    v.z = fmaxf(v.z * scale[j+2] + shift[j+2], 0.0f);
    v.w = fmaxf(v.w * scale[j+3] + shift[j+3], 0.0f);
    *(float4*)(h + base) = v;
}

// ---------------- prep: transposed bf16 weights (fragment-ready) ----------------
__global__ void k_prep(const float* __restrict__ We, const float* __restrict__ Wm1,
                       short* __restrict__ WteT, short* __restrict__ WmsT, short* __restrict__ WmdT)
{
    int j = threadIdx.x;  // 128
    for (int k = 0; k < 32; k++)
        WteT[j * 32 + k] = (k < 16) ? f2b(We[k * 128 + j]) : (short)0;
    for (int k = 0; k < 128; k++) {
        WmsT[j * 128 + k] = f2b(Wm1[k * 128 + j]);
        WmdT[j * 128 + k] = f2b(Wm1[(128 + k) * 128 + j]);
    }
}

// ---------------- fold bne into Wm1[256:384] -> W1pT (bf16, transposed) ----------------
__global__ void k_fold_e(const float* __restrict__ ssum, const float* __restrict__ ssq,
    const float* __restrict__ g, const float* __restrict__ b,
    const float* __restrict__ Wm1, const float* __restrict__ bm1,
    short* __restrict__ W1pT, float* __restrict__ bm1p)
{
    __shared__ float sa[128], sc[128];
    int tid = threadIdx.x;
    float m = ssum[tid] / (float)NE;
    float var = ssq[tid] / (float)NE - m * m;
    float rs = rsqrtf(var + 1e-5f);
    float a = g[tid] * rs;
    sa[tid] = a; sc[tid] = b[tid] - m * a;
    __syncthreads();
    float acc = bm1[tid];
    for (int k = 0; k < 128; k++) {
        float w = Wm1[(256 + k) * 128 + tid];
        W1pT[tid * 128 + k] = f2b(sa[k] * w);
        acc += sc[k] * w;
    }
    bm1p[tid] = acc;
}

// ---------------- fold bnm into Wm2 -> W2pT (bf16, transposed) ----------------
__global__ void k_fold_m(const float* __restrict__ ssum, const float* __restrict__ ssq,
    const float* __restrict__ g, const float* __restrict__ b,
    const float* __restrict__ Wm2, const float* __restrict__ bm2,
    short* __restrict__ W2pT, float* __restrict__ b2p)
{
    __shared__ float sa[128], sc[128];
    int tid = threadIdx.x;
    float m = ssum[tid] / (float)NE;
    float var = ssq[tid] / (float)NE - m * m;
    float rs = rsqrtf(var + 1e-5f);
    float a = g[tid] * rs;
    sa[tid] = a; sc[tid] = b[tid] - m * a;
    __syncthreads();
    if (tid < 64) {
        float acc = bm2[tid];
        for (int k = 0; k < 128; k++) {
            float w = Wm2[k * 64 + tid];
            W2pT[tid * 128 + k] = f2b(sa[k] * w);
            acc += sc[k] * w;
        }
        b2p[tid] = acc;
    }
}

// ---------------- node projection C = A @ W via MFMA (N=100000, 128x128) ----------------
__global__ __launch_bounds__(256) void k_proj_mfma(
    const float* __restrict__ A, const short* __restrict__ WT, float* __restrict__ C)
{
    __shared__ __align__(16) short sA[32][136];
    const int tid = threadIdx.x;
    const int wave = tid >> 6, lane = tid & 63, quad = lane >> 4, ln = lane & 15;
    const int waveM = wave >> 1, waveN = wave & 1;
    const int colbase = 64 * waveN, row16 = 16 * waveM;
    bf16x8 bW[4][4];
    #pragma unroll
    for (int nt = 0; nt < 4; nt++)
        #pragma unroll
        for (int kk = 0; kk < 4; kk++)
            bW[nt][kk] = *(const bf16x8*)(WT + (colbase + nt * 16 + ln) * 128 + kk * 32 + quad * 8);
    f32x4 zero = {0.f, 0.f, 0.f, 0.f};
    for (int t = blockIdx.x; t < NN / 32; t += gridDim.x) {
        int r0 = t * 32;
        __syncthreads();
        {
            int r = tid >> 3, c0 = (tid & 7) * 16;
            const float* p = A + (size_t)(r0 + r) * 128 + c0;
            short tmp[16];
            #pragma unroll
            for (int i = 0; i < 16; i++) tmp[i] = f2b(p[i]);
            *(bf16x8*)(&sA[r][c0])     = *(bf16x8*)tmp;
            *(bf16x8*)(&sA[r][c0 + 8]) = *(bf16x8*)(tmp + 8);
        }
        __syncthreads();
        f32x4 acc[4] = {zero, zero, zero, zero};
        #pragma unroll
        for (int kk = 0; kk < 4; kk++) {
            bf16x8 a = *(const bf16x8*)(&sA[row16 + ln][kk * 32 + quad * 8]);
            #pragma unroll
            for (int nt = 0; nt < 4; nt++)
                acc[nt] = __builtin_amdgcn_mfma_f32_16x16x32_bf16(a, bW[nt][kk], acc[nt], 0, 0, 0);
        }
        #pragma unroll
        for (int nt = 0; nt < 4; nt++) {
            int col = colbase + nt * 16 + ln;
            #pragma unroll
            for (int r = 0; r < 4; r++)
                C[(size_t)(r0 + row16 + quad * 4 + r) * 128 + col] = acc[nt][r];
        }
    }
}

// ---------------- edge pipeline via MFMA ----------------
// MODE 0: bne stats of t = relu(ea@We+be)
// MODE 1: v = relu(t@W1p + bm1p + hs[es] + hd[et]); bnm stats
// MODE 2: recompute v; z2 = relu(v@W2p + b2p); out = z2@Wm3 + bm3
template<int MODE>
__global__ __launch_bounds__(256) void k_edge_mfma(
    const float* __restrict__ ea,
    const short* __restrict__ WteT, const float* __restrict__ be,
    const short* __restrict__ W1pT, const float* __restrict__ bm1p,
    const float* __restrict__ hs, const float* __restrict__ hd,
    const int* __restrict__ esrc, const int* __restrict__ etgt,
    const short* __restrict__ W2pT, const float* __restrict__ b2p,
    const float* __restrict__ Wm3, const float* __restrict__ bm3,
    float* __restrict__ ssum, float* __restrict__ ssq,
    float* __restrict__ outp)
{
    __shared__ __align__(16) short sT[32][136];
    __shared__ float sRed[2][128];
    __shared__ __align__(16) short sW2[64][136];
    __shared__ float sZ[32][69];
    __shared__ float sW3[64];

    const int tid = threadIdx.x;
    const int wave = tid >> 6, lane = tid & 63;
    const int quad = lane >> 4, ln = lane & 15;
    const int waveM = wave >> 1, waveN = wave & 1;
    const int colbase = 64 * waveN, row16 = 16 * waveM;

    if (MODE < 2) {
        if (tid < 128) { sRed[0][tid] = 0.f; sRed[1][tid] = 0.f; }
    }
    if (MODE == 2) {
        int q = tid >> 2, kb = (tid & 3) * 32;
        const bf16x8* src = (const bf16x8*)(W2pT + q * 128 + kb);
        bf16x8* dst = (bf16x8*)(&sW2[q][kb]);
        dst[0] = src[0]; dst[1] = src[1]; dst[2] = src[2]; dst[3] = src[3];
        if (tid < 64) sW3[tid] = Wm3[tid];
    }

    // loop-invariant B fragments in registers
    bf16x8 bWe[4], bW1[4][4];
    #pragma unroll
    for (int nt = 0; nt < 4; nt++) {
        bWe[nt] = *(const bf16x8*)(WteT + (colbase + nt * 16 + ln) * 32 + quad * 8);
        if (MODE >= 1) {
            #pragma unroll
            for (int kk = 0; kk < 4; kk++)
                bW1[nt][kk] = *(const bf16x8*)(W1pT + (colbase + nt * 16 + ln) * 128 + kk * 32 + quad * 8);
        }
    }
    float bec[4], bmc[4];
    #pragma unroll
    for (int nt = 0; nt < 4; nt++) {
        bec[nt] = be[colbase + nt * 16 + ln];
        bmc[nt] = (MODE >= 1) ? bm1p[colbase + nt * 16 + ln] : 0.f;
    }
    float b2c[2];
    if (MODE == 2) { b2c[0] = b2p[32 * waveN + ln]; b2c[1] = b2p[32 * waveN + 16 + ln]; }
    float bm3v = (MODE == 2) ? bm3[0] : 0.f;

    float s1[4] = {0,0,0,0}, s2[4] = {0,0,0,0};
    f32x4 zero = {0.f, 0.f, 0.f, 0.f};
    __syncthreads();

    for (int t = blockIdx.x; t < NE / 32; t += gridDim.x) {
        const int e0 = t * 32;
        // ---- t-GEMM (K padded to 32) ----
        bf16x8 aE;
        #pragma unroll
        for (int i = 0; i < 8; i++) aE[i] = 0;
        if (quad < 2) {
            const float* p = ea + (size_t)(e0 + row16 + ln) * 16 + quad * 8;
            float4 f0 = *(const float4*)p, f1 = *(const float4*)(p + 4);
            aE[0]=f2b(f0.x); aE[1]=f2b(f0.y); aE[2]=f2b(f0.z); aE[3]=f2b(f0.w);
            aE[4]=f2b(f1.x); aE[5]=f2b(f1.y); aE[6]=f2b(f1.z); aE[7]=f2b(f1.w);
        }
        f32x4 tacc[4];
        #pragma unroll
        for (int nt = 0; nt < 4; nt++)
            tacc[nt] = __builtin_amdgcn_mfma_f32_16x16x32_bf16(aE, bWe[nt], zero, 0, 0, 0);

        if (MODE == 0) {
            #pragma unroll
            for (int nt = 0; nt < 4; nt++)
                #pragma unroll
                for (int r = 0; r < 4; r++) {
                    float v = fmaxf(tacc[nt][r] + bec[nt], 0.f);
                    s1[nt] += v; s2[nt] += v * v;
                }
            continue;
        }

        __syncthreads();   // prev-iter sT reads done
        #pragma unroll
        for (int nt = 0; nt < 4; nt++) {
            int col = colbase + nt * 16 + ln;
            #pragma unroll
            for (int r = 0; r < 4; r++)
                sT[row16 + quad * 4 + r][col] = f2b(fmaxf(tacc[nt][r] + bec[nt], 0.f));
        }
        __syncthreads();

        // ---- u-GEMM: t @ W1p ----
        f32x4 uacc[4] = {zero, zero, zero, zero};
        #pragma unroll
        for (int kk = 0; kk < 4; kk++) {
            bf16x8 aU = *(const bf16x8*)(&sT[row16 + ln][kk * 32 + quad * 8]);
            #pragma unroll
            for (int nt = 0; nt < 4; nt++)
                uacc[nt] = __builtin_amdgcn_mfma_f32_16x16x32_bf16(aU, bW1[nt][kk], uacc[nt], 0, 0, 0);
        }

        // ---- epilogue: gathers + v ----
        int4 is4 = *(const int4*)(esrc + e0 + row16 + quad * 4);
        int4 it4 = *(const int4*)(etgt + e0 + row16 + quad * 4);
        int isv[4] = {is4.x, is4.y, is4.z, is4.w};
        int itv[4] = {it4.x, it4.y, it4.z, it4.w};

        if (MODE == 1) {
            #pragma unroll
            for (int nt = 0; nt < 4; nt++) {
                int col = colbase + nt * 16 + ln;
                #pragma unroll
                for (int r = 0; r < 4; r++) {
                    float v = uacc[nt][r] + bmc[nt]
                            + hs[(size_t)isv[r] * 128 + col] + hd[(size_t)itv[r] * 128 + col];
                    v = fmaxf(v, 0.f);
                    s1[nt] += v; s2[nt] += v * v;
                }
            }
        } else {
            __syncthreads();   // u-GEMM sT reads done
            #pragma unroll
            for (int nt = 0; nt < 4; nt++) {
                int col = colbase + nt * 16 + ln;
                #pragma unroll
                for (int r = 0; r < 4; r++) {
                    float v = uacc[nt][r] + bmc[nt]
                            + hs[(size_t)isv[r] * 128 + col] + hd[(size_t)itv[r] * 128 + col];
                    sT[row16 + quad * 4 + r][col] = f2b(fmaxf(v, 0.f));
                }
            }
            __syncthreads();
            // ---- v @ W2p ----
            f32x4 vacc[2] = {zero, zero};
            #pragma unroll
            for (int kk = 0; kk < 4; kk++) {
                bf16x8 aV = *(const bf16x8*)(&sT[row16 + ln][kk * 32 + quad * 8]);
                #pragma unroll
                for (int n2 = 0; n2 < 2; n2++) {
                    bf16x8 bV = *(const bf16x8*)(&sW2[32 * waveN + n2 * 16 + ln][kk * 32 + quad * 8]);
                    vacc[n2] = __builtin_amdgcn_mfma_f32_16x16x32_bf16(aV, bV, vacc[n2], 0, 0, 0);
                }
            }
            #pragma unroll
            for (int n2 = 0; n2 < 2; n2++) {
                int col2 = 32 * waveN + n2 * 16 + ln;
                #pragma unroll
                for (int r = 0; r < 4; r++)
                    sZ[row16 + quad * 4 + r][col2] = fmaxf(vacc[n2][r] + b2c[n2], 0.f);
            }
            __syncthreads();
            // ---- z2 @ Wm3 ----
            if (wave == 0) {
                int rw = lane & 31, half = lane >> 5;
                float o = 0.f;
                #pragma unroll
                for (int k2 = 0; k2 < 32; k2++)
                    o += sZ[rw][half * 32 + k2] * sW3[half * 32 + k2];
                o += __shfl_down(o, 32);
                if (lane < 32) outp[e0 + rw] = o + bm3v;
            }
        }
    }

    if (MODE < 2) {
        #pragma unroll
        for (int nt = 0; nt < 4; nt++) {
            float a1 = s1[nt], a2 = s2[nt];
            a1 += __shfl_down(a1, 32); a1 += __shfl_down(a1, 16);
            a2 += __shfl_down(a2, 32); a2 += __shfl_down(a2, 16);
            if (quad == 0) {
                atomicAdd(&sRed[0][colbase + nt * 16 + ln], a1);
                atomicAdd(&sRed[1][colbase + nt * 16 + ln], a2);
            }
        }
        __syncthreads();
        if (tid < 128) {
            atomicAdd(&ssum[tid], sRed[0][tid]);
            atomicAdd(&ssq[tid],  sRed[1][tid]);
        }
    }
}

extern "C" void kernel_launch(void* const* d_in, const int* in_sizes, int n_in,
                              void* d_out, int out_size, void* d_ws, size_t ws_size,
                              hipStream_t stream) {
    const float* x     = (const float*)d_in[0];
    const int*   ei    = (const int*)  d_in[1];
    const float* eattr = (const float*)d_in[2];
    const int*   esrc  = (const int*)  d_in[3];
    const int*   etgt  = (const int*)  d_in[4];
    const float* W1l = (const float*)d_in[5];  const float* b1 = (const float*)d_in[6];
    const float* W1r = (const float*)d_in[7];
    const float* W2l = (const float*)d_in[8];  const float* b2 = (const float*)d_in[9];
    const float* W2r = (const float*)d_in[10];
    const float* bn1_g = (const float*)d_in[11]; const float* bn1_b = (const float*)d_in[12];
    const float* bn2_g = (const float*)d_in[13]; const float* bn2_b = (const float*)d_in[14];
    const float* We  = (const float*)d_in[15]; const float* be  = (const float*)d_in[16];
    const float* bne_g = (const float*)d_in[17]; const float* bne_b = (const float*)d_in[18];
    const float* Wm1 = (const float*)d_in[19]; const float* bm1 = (const float*)d_in[20];
    const float* bnm_g = (const float*)d_in[21]; const float* bnm_b = (const float*)d_in[22];
    const float* Wm2 = (const float*)d_in[23]; const float* bm2 = (const float*)d_in[24];
    const float* Wm3 = (const float*)d_in[25]; const float* bm3 = (const float*)d_in[26];
    float* out = (float*)d_out;

    float* ws = (float*)d_ws;
    size_t off = 0;
    float* S0  = ws + off; off += (size_t)NN * 128;   // agg -> hs
    float* S1  = ws + off; off += (size_t)NN * 128;   // h1 -> hd
    float* S2  = ws + off; off += (size_t)NN * 128;   // h2
    float* cnt = ws + off; off += NN;
    float* st  = ws + off; off += 1024;
    float* sc1 = ws + off; off += 128;  float* sh1 = ws + off; off += 128;
    float* sc2 = ws + off; off += 128;  float* sh2 = ws + off; off += 128;
    float* bm1p= ws + off; off += 128;
    float* b2p = ws + off; off += 64;
    short* WteT = (short*)(ws + off); off += 2048;    // 128x32 bf16
    short* W1pT = (short*)(ws + off); off += 8192;    // 128x128 bf16
    short* WmsT = (short*)(ws + off); off += 8192;
    short* WmdT = (short*)(ws + off); off += 8192;
    short* W2pT = (short*)(ws + off); off += 4096;    // 64x128 bf16

    hipMemsetAsync(S0, 0, (size_t)NN * 32 * 4, stream);
    hipMemsetAsync(cnt, 0, (size_t)NN * 4, stream);
    hipMemsetAsync(st, 0, 1024 * 4, stream);

    // weight prep (no deps)
    k_prep<<<1, 128, 0, stream>>>(We, Wm1, WteT, WmsT, WmdT);

    // edge bne stats (independent of node path)
    k_edge_mfma<0><<<1024, 256, 0, stream>>>(eattr, WteT, be, W1pT, bm1p, S0, S1,
        esrc, etgt, W2pT, b2p, Wm3, bm3, st + 512, st + 640, out);
    k_fold_e<<<1, 128, 0, stream>>>(st + 512, st + 640, bne_g, bne_b, Wm1, bm1, W1pT, bm1p);

    // ---- layer 1 ----
    k_agg1<<<(NE * 32) / 256, 256, 0, stream>>>(x, ei, S0, cnt);
    k_node_l1<<<NN / 32, 256, 0, stream>>>(S0, cnt, x, W1l, W1r, b1, S1, st + 0, st + 128);
    k_bn_fin<<<1, 128, 0, stream>>>(st + 0, st + 128, bn1_g, bn1_b, (float)NN, sc1, sh1);
    k_bnrelu<<<(NN * 128 / 4) / 256, 256, 0, stream>>>(S1, sc1, sh1);

    // ---- layer 2 ----
    hipMemsetAsync(S0, 0, (size_t)NN * 128 * 4, stream);
    k_agg2<<<(NE * 128) / 256, 256, 0, stream>>>(S1, ei, S0);
    k_node_l2<<<NN / 16, 256, 0, stream>>>(S0, cnt, S1, W2l, W2r, b2, S2, st + 256, st + 384);
    k_bn_fin<<<1, 128, 0, stream>>>(st + 256, st + 384, bn2_g, bn2_b, (float)NN, sc2, sh2);
    k_bnrelu<<<(NN * 128 / 4) / 256, 256, 0, stream>>>(S2, sc2, sh2);

    // ---- node projections (hs -> S0, hd -> S1) ----
    k_proj_mfma<<<640, 256, 0, stream>>>(S2, WmsT, S0);
    k_proj_mfma<<<640, 256, 0, stream>>>(S2, WmdT, S1);

    // ---- edge main (v + bnm stats) ----
    k_edge_mfma<1><<<1280, 256, 0, stream>>>(eattr, WteT, be, W1pT, bm1p, S0, S1,
        esrc, etgt, W2pT, b2p, Wm3, bm3, st + 768, st + 896, out);
    k_fold_m<<<1, 128, 0, stream>>>(st + 768, st + 896, bnm_g, bnm_b, Wm2, bm2, W2pT, b2p);

    // ---- edge final ----
    k_edge_mfma<2><<<1280, 256, 0, stream>>>(eattr, WteT, be, W1pT, bm1p, S0, S1,
        esrc, etgt, W2pT, b2p, Wm3, bm3, nullptr, nullptr, out);
}

// Round 3
// 1165.390 us; speedup vs baseline: 2.8888x; 1.4027x over previous
//
#include <hip/hip_runtime.h>
#include <hip/hip_bf16.h>

#define NN 100000
#define NE 800000

typedef __attribute__((ext_vector_type(8))) short bf16x8;
typedef __attribute__((ext_vector_type(4))) float f32x4;

__device__ __forceinline__ short f2b(float f) {
    unsigned u = __float_as_uint(f);
    unsigned r = (u + 0x7fffu + ((u >> 16) & 1u)) >> 16;
    return (short)r;
}
__device__ __forceinline__ float b2f(short s) {
    return __uint_as_float(((unsigned)(unsigned short)s) << 16);
}

// ---------------- CSR build ----------------
__global__ __launch_bounds__(256) void k_hist(const int* __restrict__ ei, int* __restrict__ deg)
{
    int e = blockIdx.x * 256 + threadIdx.x;
    if (e < NE) atomicAdd(&deg[ei[NE + e]], 1);
}

__global__ __launch_bounds__(1024) void k_scan(const int* __restrict__ deg,
    int* __restrict__ rowptr, int* __restrict__ wp)
{
    __shared__ int part[1024];
    const int CH = 98;  // 1024*98 >= 100000
    int t = threadIdx.x;
    int beg = t * CH, end = min(beg + CH, NN);
    int s = 0;
    for (int i = beg; i < end; i++) s += deg[i];
    part[t] = s;
    __syncthreads();
    for (int ofs = 1; ofs < 1024; ofs <<= 1) {
        int v = (t >= ofs) ? part[t - ofs] : 0;
        __syncthreads();
        part[t] += v;
        __syncthreads();
    }
    int base = (t == 0) ? 0 : part[t - 1];
    for (int i = beg; i < end; i++) {
        rowptr[i] = base; wp[i] = base;
        base += deg[i];
    }
    if (t == 0) rowptr[NN] = part[1023];
}

__global__ __launch_bounds__(256) void k_scatter(const int* __restrict__ ei,
    int* __restrict__ wp, int* __restrict__ elist)
{
    int e = blockIdx.x * 256 + threadIdx.x;
    if (e < NE) {
        int d = ei[NE + e];
        int pos = atomicAdd(&wp[d], 1);
        elist[pos] = ei[e];
    }
}

// ---------------- gather aggregation (no atomics) ----------------
__global__ __launch_bounds__(256) void k_gagg1(const float* __restrict__ x,
    const int* __restrict__ rowptr, const int* __restrict__ elist, float* __restrict__ meanX)
{
    int n = blockIdx.x * 8 + (threadIdx.x >> 5);
    int j = threadIdx.x & 31;
    int b = rowptr[n], e = rowptr[n + 1];
    float acc = 0.f;
    for (int i = b; i < e; i++) {
        int s = elist[i];
        acc += x[(size_t)s * 32 + j];
    }
    float inv = (e > b) ? 1.0f / (float)(e - b) : 1.0f;
    meanX[(size_t)n * 32 + j] = acc * inv;
}

__global__ __launch_bounds__(256) void k_gagg2(const short* __restrict__ h1b,
    const int* __restrict__ rowptr, const int* __restrict__ elist,
    const float* __restrict__ sc1, const float* __restrict__ sh1, short* __restrict__ m2b)
{
    int n = blockIdx.x * 2 + (threadIdx.x >> 7);
    int j = threadIdx.x & 127;
    float sc = sc1[j], sh = sh1[j];
    int b = rowptr[n], e = rowptr[n + 1];
    float acc = 0.f;
    for (int i = b; i < e; i++) {
        int s = elist[i];
        acc += fmaxf(b2f(h1b[(size_t)s * 128 + j]) * sc + sh, 0.f);
    }
    float inv = (e > b) ? 1.0f / (float)(e - b) : 1.0f;
    m2b[(size_t)n * 128 + j] = f2b(acc * inv);
}

// ---------------- SAGE layer 1 (fp32 VALU, K=32+32), writes h1b bf16 + stats ----------------
__global__ __launch_bounds__(256) void k_node_l1(
    const float* __restrict__ meanX, const float* __restrict__ x,
    const float* __restrict__ Wl, const float* __restrict__ Wr,
    const float* __restrict__ bias,
    short* __restrict__ outp, float* __restrict__ ssum, float* __restrict__ ssq)
{
    __shared__ __align__(16) float sWl[32][128];
    __shared__ __align__(16) float sWr[32][128];
    __shared__ __align__(16) float sA[32][36];
    __shared__ __align__(16) float sB[32][36];
    __shared__ float red[2][128], red2[2][128];
    int tid = threadIdx.x;
    int j = tid & 127, rg = tid >> 7;
    int r0 = blockIdx.x * 32;

    for (int f = tid * 4; f < 4096; f += 1024) {
        *(float4*)((float*)sWl + f) = *(const float4*)(Wl + f);
        *(float4*)((float*)sWr + f) = *(const float4*)(Wr + f);
    }
    {
        int r = tid >> 3, c = (tid & 7) * 4;
        *(float4*)(&sA[r][c]) = *(const float4*)(meanX + (size_t)(r0 + r) * 32 + c);
        *(float4*)(&sB[r][c]) = *(const float4*)(x + (size_t)(r0 + r) * 32 + c);
    }
    __syncthreads();

    float acc[16];
    #pragma unroll
    for (int r = 0; r < 16; r++) acc[r] = 0.0f;
    int rb = rg * 16;
    #pragma unroll
    for (int kq = 0; kq < 8; kq++) {
        int k = kq * 4;
        float wl0 = sWl[k][j], wl1 = sWl[k+1][j], wl2 = sWl[k+2][j], wl3 = sWl[k+3][j];
        float wr0 = sWr[k][j], wr1 = sWr[k+1][j], wr2 = sWr[k+2][j], wr3 = sWr[k+3][j];
        #pragma unroll
        for (int r = 0; r < 16; r++) {
            float4 a = *(float4*)(&sA[rb + r][k]);
            float4 b = *(float4*)(&sB[rb + r][k]);
            acc[r] += a.x*wl0 + a.y*wl1 + a.z*wl2 + a.w*wl3
                    + b.x*wr0 + b.y*wr1 + b.z*wr2 + b.w*wr3;
        }
    }
    float bj = bias[j];
    float s1 = 0.0f, s2 = 0.0f;
    #pragma unroll
    for (int r = 0; r < 16; r++) {
        float v = acc[r] + bj;
        outp[(size_t)(r0 + rb + r) * 128 + j] = f2b(v);
        s1 += v; s2 += v * v;
    }
    red[rg][j] = s1; red2[rg][j] = s2;
    __syncthreads();
    if (rg == 0) {
        atomicAdd(&ssum[j], red[0][j] + red[1][j]);
        atomicAdd(&ssq[j],  red2[0][j] + red2[1][j]);
    }
}

// ---------------- SAGE layer 2 via MFMA: h2 = [mean | bnrelu(h1)] @ W2c + b2 ----------------
__global__ __launch_bounds__(256) void k_node_l2m(
    const short* __restrict__ m2b, const short* __restrict__ h1b,
    const float* __restrict__ sc1, const float* __restrict__ sh1,
    const short* __restrict__ W2cT, const float* __restrict__ bias,
    short* __restrict__ h2b, float* __restrict__ ssum, float* __restrict__ ssq)
{
    __shared__ __align__(16) short sK[32][264];
    __shared__ float sRed[2][128];
    __shared__ float sS[128], sH[128];
    const int tid = threadIdx.x;
    const int wave = tid >> 6, lane = tid & 63, quad = lane >> 4, ln = lane & 15;
    const int waveM = wave >> 1, waveN = wave & 1;
    const int colbase = 64 * waveN, row16 = 16 * waveM;
    if (tid < 128) { sS[tid] = sc1[tid]; sH[tid] = sh1[tid]; sRed[0][tid] = 0.f; sRed[1][tid] = 0.f; }

    bf16x8 bW[4][8];
    #pragma unroll
    for (int nt = 0; nt < 4; nt++)
        #pragma unroll
        for (int kk = 0; kk < 8; kk++)
            bW[nt][kk] = *(const bf16x8*)(W2cT + (size_t)(colbase + nt * 16 + ln) * 256 + kk * 32 + quad * 8);
    float bc[4];
    #pragma unroll
    for (int nt = 0; nt < 4; nt++) bc[nt] = bias[colbase + nt * 16 + ln];

    float s1[4] = {0,0,0,0}, s2[4] = {0,0,0,0};
    f32x4 zero = {0.f, 0.f, 0.f, 0.f};
    __syncthreads();

    for (int t = blockIdx.x; t < NN / 32; t += gridDim.x) {
        int r0 = t * 32;
        __syncthreads();
        {
            int r = tid >> 3, seg = tid & 7;
            if (seg < 4) {
                const bf16x8* src = (const bf16x8*)(m2b + (size_t)(r0 + r) * 128 + seg * 32);
                bf16x8* dst = (bf16x8*)(&sK[r][seg * 32]);
                dst[0] = src[0]; dst[1] = src[1]; dst[2] = src[2]; dst[3] = src[3];
            } else {
                int c0 = (seg - 4) * 32;
                const short* src = h1b + (size_t)(r0 + r) * 128 + c0;
                short tmp[32];
                #pragma unroll
                for (int i = 0; i < 32; i++)
                    tmp[i] = f2b(fmaxf(b2f(src[i]) * sS[c0 + i] + sH[c0 + i], 0.f));
                bf16x8* dst = (bf16x8*)(&sK[r][128 + c0]);
                dst[0] = *(bf16x8*)(tmp); dst[1] = *(bf16x8*)(tmp + 8);
                dst[2] = *(bf16x8*)(tmp + 16); dst[3] = *(bf16x8*)(tmp + 24);
            }
        }
        __syncthreads();
        f32x4 acc[4] = {zero, zero, zero, zero};
        #pragma unroll
        for (int kk = 0; kk < 8; kk++) {
            bf16x8 a = *(const bf16x8*)(&sK[row16 + ln][kk * 32 + quad * 8]);
            #pragma unroll
            for (int nt = 0; nt < 4; nt++)
                acc[nt] = __builtin_amdgcn_mfma_f32_16x16x32_bf16(a, bW[nt][kk], acc[nt], 0, 0, 0);
        }
        #pragma unroll
        for (int nt = 0; nt < 4; nt++) {
            int col = colbase + nt * 16 + ln;
            #pragma unroll
            for (int r = 0; r < 4; r++) {
                float v = acc[nt][r] + bc[nt];
                h2b[(size_t)(r0 + row16 + quad * 4 + r) * 128 + col] = f2b(v);
                s1[nt] += v; s2[nt] += v * v;
            }
        }
    }
    #pragma unroll
    for (int nt = 0; nt < 4; nt++) {
        float a1 = s1[nt], a2 = s2[nt];
        a1 += __shfl_down(a1, 32); a1 += __shfl_down(a1, 16);
        a2 += __shfl_down(a2, 32); a2 += __shfl_down(a2, 16);
        if (quad == 0) {
            atomicAdd(&sRed[0][colbase + nt * 16 + ln], a1);
            atomicAdd(&sRed[1][colbase + nt * 16 + ln], a2);
        }
    }
    __syncthreads();
    if (tid < 128) {
        atomicAdd(&ssum[tid], sRed[0][tid]);
        atomicAdd(&ssq[tid],  sRed[1][tid]);
    }
}

// ---------------- batch-norm finalize ----------------
__global__ void k_bn_fin(const float* __restrict__ ssum, const float* __restrict__ ssq,
    const float* __restrict__ g, const float* __restrict__ b, float count,
    float* __restrict__ scale, float* __restrict__ shift)
{
    int j = threadIdx.x;
    float m = ssum[j] / count;
    float var = ssq[j] / count - m * m;
    float rs = rsqrtf(var + 1e-5f);
    float sc = g[j] * rs;
    scale[j] = sc;
    shift[j] = b[j] - m * sc;
}

// ---------------- prep: transposed bf16 weights ----------------
__global__ void k_prep(const float* __restrict__ We, const float* __restrict__ Wm1,
                       const float* __restrict__ W2l, const float* __restrict__ W2r,
                       short* __restrict__ WteT, short* __restrict__ WmsT,
                       short* __restrict__ WmdT, short* __restrict__ W2cT)
{
    int j = threadIdx.x;  // 128
    int b = blockIdx.x;
    if (b == 0) {
        for (int k = 0; k < 32; k++)
            WteT[j * 32 + k] = (k < 16) ? f2b(We[k * 128 + j]) : (short)0;
    } else if (b == 1) {
        for (int k = 0; k < 128; k++) WmsT[j * 128 + k] = f2b(Wm1[k * 128 + j]);
    } else if (b == 2) {
        for (int k = 0; k < 128; k++) WmdT[j * 128 + k] = f2b(Wm1[(128 + k) * 128 + j]);
    } else if (b == 3) {
        for (int k = 0; k < 128; k++) W2cT[j * 256 + k] = f2b(W2l[k * 128 + j]);
    } else {
        for (int k = 0; k < 128; k++) W2cT[j * 256 + 128 + k] = f2b(W2r[k * 128 + j]);
    }
}

// ---------------- fold bne into Wm1[256:384] -> W1pT ----------------
__global__ void k_fold_e(const float* __restrict__ ssum, const float* __restrict__ ssq,
    const float* __restrict__ g, const float* __restrict__ b,
    const float* __restrict__ Wm1, const float* __restrict__ bm1,
    short* __restrict__ W1pT, float* __restrict__ bm1p)
{
    __shared__ float sa[128], sc[128];
    int tid = threadIdx.x;
    float m = ssum[tid] / (float)NE;
    float var = ssq[tid] / (float)NE - m * m;
    float rs = rsqrtf(var + 1e-5f);
    float a = g[tid] * rs;
    sa[tid] = a; sc[tid] = b[tid] - m * a;
    __syncthreads();
    float acc = bm1[tid];
    for (int k = 0; k < 128; k++) {
        float w = Wm1[(256 + k) * 128 + tid];
        W1pT[tid * 128 + k] = f2b(sa[k] * w);
        acc += sc[k] * w;
    }
    bm1p[tid] = acc;
}

// ---------------- fold bnm into Wm2 -> W2pT ----------------
__global__ void k_fold_m(const float* __restrict__ ssum, const float* __restrict__ ssq,
    const float* __restrict__ g, const float* __restrict__ b,
    const float* __restrict__ Wm2, const float* __restrict__ bm2,
    short* __restrict__ W2pT, float* __restrict__ b2p)
{
    __shared__ float sa[128], sc[128];
    int tid = threadIdx.x;
    float m = ssum[tid] / (float)NE;
    float var = ssq[tid] / (float)NE - m * m;
    float rs = rsqrtf(var + 1e-5f);
    float a = g[tid] * rs;
    sa[tid] = a; sc[tid] = b[tid] - m * a;
    __syncthreads();
    if (tid < 64) {
        float acc = bm2[tid];
        for (int k = 0; k < 128; k++) {
            float w = Wm2[k * 64 + tid];
            W2pT[tid * 128 + k] = f2b(sa[k] * w);
            acc += sc[k] * w;
        }
        b2p[tid] = acc;
    }
}

// ---------------- node projection: C(bf16) = bnrelu(h2b) @ W via MFMA ----------------
__global__ __launch_bounds__(256) void k_proj_mfma(
    const short* __restrict__ h2b, const float* __restrict__ sc2, const float* __restrict__ sh2,
    const short* __restrict__ WT, short* __restrict__ C)
{
    __shared__ __align__(16) short sA[32][136];
    __shared__ float sS[128], sH[128];
    const int tid = threadIdx.x;
    const int wave = tid >> 6, lane = tid & 63, quad = lane >> 4, ln = lane & 15;
    const int waveM = wave >> 1, waveN = wave & 1;
    const int colbase = 64 * waveN, row16 = 16 * waveM;
    if (tid < 128) { sS[tid] = sc2[tid]; sH[tid] = sh2[tid]; }
    bf16x8 bW[4][4];
    #pragma unroll
    for (int nt = 0; nt < 4; nt++)
        #pragma unroll
        for (int kk = 0; kk < 4; kk++)
            bW[nt][kk] = *(const bf16x8*)(WT + (colbase + nt * 16 + ln) * 128 + kk * 32 + quad * 8);
    f32x4 zero = {0.f, 0.f, 0.f, 0.f};
    __syncthreads();
    for (int t = blockIdx.x; t < NN / 32; t += gridDim.x) {
        int r0 = t * 32;
        __syncthreads();
        {
            int r = tid >> 3, c0 = (tid & 7) * 16;
            const short* p = h2b + (size_t)(r0 + r) * 128 + c0;
            short tmp[16];
            #pragma unroll
            for (int i = 0; i < 16; i++)
                tmp[i] = f2b(fmaxf(b2f(p[i]) * sS[c0 + i] + sH[c0 + i], 0.f));
            *(bf16x8*)(&sA[r][c0])     = *(bf16x8*)tmp;
            *(bf16x8*)(&sA[r][c0 + 8]) = *(bf16x8*)(tmp + 8);
        }
        __syncthreads();
        f32x4 acc[4] = {zero, zero, zero, zero};
        #pragma unroll
        for (int kk = 0; kk < 4; kk++) {
            bf16x8 a = *(const bf16x8*)(&sA[row16 + ln][kk * 32 + quad * 8]);
            #pragma unroll
            for (int nt = 0; nt < 4; nt++)
                acc[nt] = __builtin_amdgcn_mfma_f32_16x16x32_bf16(a, bW[nt][kk], acc[nt], 0, 0, 0);
        }
        #pragma unroll
        for (int nt = 0; nt < 4; nt++) {
            int col = colbase + nt * 16 + ln;
            #pragma unroll
            for (int r = 0; r < 4; r++)
                C[(size_t)(r0 + row16 + quad * 4 + r) * 128 + col] = f2b(acc[nt][r]);
        }
    }
}

// ---------------- edge pipeline via MFMA ----------------
// MODE 0: bne stats of t = relu(ea@We+be)
// MODE 1: v = relu(t@W1p + bm1p + hs[es] + hd[et]); bnm stats; optional store v (bf16)
// MODE 2: recompute v; z2 = relu(v@W2p + b2p); out = z2@Wm3 + bm3
// MODE 3: load v from vbuf; z2/out as MODE 2
template<int MODE, bool STOREV = false>
__global__ __launch_bounds__(256) void k_edge_mfma(
    const float* __restrict__ ea,
    const short* __restrict__ WteT, const float* __restrict__ be,
    const short* __restrict__ W1pT, const float* __restrict__ bm1p,
    const short* __restrict__ hs, const short* __restrict__ hd,
    const int* __restrict__ esrc, const int* __restrict__ etgt,
    const short* __restrict__ W2pT, const float* __restrict__ b2p,
    const float* __restrict__ Wm3, const float* __restrict__ bm3,
    float* __restrict__ ssum, float* __restrict__ ssq,
    short* __restrict__ vbuf, float* __restrict__ outp)
{
    __shared__ __align__(16) short sT[32][136];
    __shared__ float sRed[2][128];
    __shared__ __align__(16) short sW2[64][136];
    __shared__ float sZ[32][69];
    __shared__ float sW3[64];

    const int tid = threadIdx.x;
    const int wave = tid >> 6, lane = tid & 63;
    const int quad = lane >> 4, ln = lane & 15;
    const int waveM = wave >> 1, waveN = wave & 1;
    const int colbase = 64 * waveN, row16 = 16 * waveM;

    if (MODE < 2) {
        if (tid < 128) { sRed[0][tid] = 0.f; sRed[1][tid] = 0.f; }
    }
    if (MODE >= 2) {
        int q = tid >> 2, kb = (tid & 3) * 32;
        const bf16x8* src = (const bf16x8*)(W2pT + q * 128 + kb);
        bf16x8* dst = (bf16x8*)(&sW2[q][kb]);
        dst[0] = src[0]; dst[1] = src[1]; dst[2] = src[2]; dst[3] = src[3];
        if (tid < 64) sW3[tid] = Wm3[tid];
    }

    bf16x8 bWe[4], bW1[4][4];
    if (MODE <= 2) {
        #pragma unroll
        for (int nt = 0; nt < 4; nt++) {
            bWe[nt] = *(const bf16x8*)(WteT + (colbase + nt * 16 + ln) * 32 + quad * 8);
            if (MODE >= 1) {
                #pragma unroll
                for (int kk = 0; kk < 4; kk++)
                    bW1[nt][kk] = *(const bf16x8*)(W1pT + (colbase + nt * 16 + ln) * 128 + kk * 32 + quad * 8);
            }
        }
    }
    float bec[4], bmc[4];
    #pragma unroll
    for (int nt = 0; nt < 4; nt++) {
        bec[nt] = (MODE <= 2) ? be[colbase + nt * 16 + ln] : 0.f;
        bmc[nt] = (MODE == 1 || MODE == 2) ? bm1p[colbase + nt * 16 + ln] : 0.f;
    }
    float b2c[2] = {0.f, 0.f};
    if (MODE >= 2) { b2c[0] = b2p[32 * waveN + ln]; b2c[1] = b2p[32 * waveN + 16 + ln]; }
    float bm3v = (MODE >= 2) ? bm3[0] : 0.f;

    float s1[4] = {0,0,0,0}, s2[4] = {0,0,0,0};
    f32x4 zero = {0.f, 0.f, 0.f, 0.f};
    __syncthreads();

    for (int t = blockIdx.x; t < NE / 32; t += gridDim.x) {
        const int e0 = t * 32;

        if (MODE == 3) {
            // ---- load v, compute z2/out ----
            f32x4 vacc[2] = {zero, zero};
            #pragma unroll
            for (int kk = 0; kk < 4; kk++) {
                bf16x8 aV = *(const bf16x8*)(vbuf + (size_t)(e0 + row16 + ln) * 128 + kk * 32 + quad * 8);
                #pragma unroll
                for (int n2 = 0; n2 < 2; n2++) {
                    bf16x8 bV = *(const bf16x8*)(&sW2[32 * waveN + n2 * 16 + ln][kk * 32 + quad * 8]);
                    vacc[n2] = __builtin_amdgcn_mfma_f32_16x16x32_bf16(aV, bV, vacc[n2], 0, 0, 0);
                }
            }
            __syncthreads();
            #pragma unroll
            for (int n2 = 0; n2 < 2; n2++) {
                int col2 = 32 * waveN + n2 * 16 + ln;
                #pragma unroll
                for (int r = 0; r < 4; r++)
                    sZ[row16 + quad * 4 + r][col2] = fmaxf(vacc[n2][r] + b2c[n2], 0.f);
            }
            __syncthreads();
            if (wave == 0) {
                int rw = lane & 31, half = lane >> 5;
                float o = 0.f;
                #pragma unroll 8
                for (int k2 = 0; k2 < 32; k2++)
                    o += sZ[rw][half * 32 + k2] * sW3[half * 32 + k2];
                o += __shfl_down(o, 32);
                if (lane < 32) outp[e0 + rw] = o + bm3v;
            }
            continue;
        }

        // ---- t-GEMM (K padded to 32) ----
        bf16x8 aE;
        #pragma unroll
        for (int i = 0; i < 8; i++) aE[i] = 0;
        if (quad < 2) {
            const float* p = ea + (size_t)(e0 + row16 + ln) * 16 + quad * 8;
            float4 f0 = *(const float4*)p, f1 = *(const float4*)(p + 4);
            aE[0]=f2b(f0.x); aE[1]=f2b(f0.y); aE[2]=f2b(f0.z); aE[3]=f2b(f0.w);
            aE[4]=f2b(f1.x); aE[5]=f2b(f1.y); aE[6]=f2b(f1.z); aE[7]=f2b(f1.w);
        }
        f32x4 tacc[4];
        #pragma unroll
        for (int nt = 0; nt < 4; nt++)
            tacc[nt] = __builtin_amdgcn_mfma_f32_16x16x32_bf16(aE, bWe[nt], zero, 0, 0, 0);

        if (MODE == 0) {
            #pragma unroll
            for (int nt = 0; nt < 4; nt++)
                #pragma unroll
                for (int r = 0; r < 4; r++) {
                    float v = fmaxf(tacc[nt][r] + bec[nt], 0.f);
                    s1[nt] += v; s2[nt] += v * v;
                }
            continue;
        }

        __syncthreads();
        #pragma unroll
        for (int nt = 0; nt < 4; nt++) {
            int col = colbase + nt * 16 + ln;
            #pragma unroll
            for (int r = 0; r < 4; r++)
                sT[row16 + quad * 4 + r][col] = f2b(fmaxf(tacc[nt][r] + bec[nt], 0.f));
        }
        __syncthreads();

        // ---- u-GEMM ----
        f32x4 uacc[4] = {zero, zero, zero, zero};
        #pragma unroll
        for (int kk = 0; kk < 4; kk++) {
            bf16x8 aU = *(const bf16x8*)(&sT[row16 + ln][kk * 32 + quad * 8]);
            #pragma unroll
            for (int nt = 0; nt < 4; nt++)
                uacc[nt] = __builtin_amdgcn_mfma_f32_16x16x32_bf16(aU, bW1[nt][kk], uacc[nt], 0, 0, 0);
        }

        int4 is4 = *(const int4*)(esrc + e0 + row16 + quad * 4);
        int4 it4 = *(const int4*)(etgt + e0 + row16 + quad * 4);
        int isv[4] = {is4.x, is4.y, is4.z, is4.w};
        int itv[4] = {it4.x, it4.y, it4.z, it4.w};

        if (MODE == 1) {
            #pragma unroll
            for (int nt = 0; nt < 4; nt++) {
                int col = colbase + nt * 16 + ln;
                #pragma unroll
                for (int r = 0; r < 4; r++) {
                    float v = uacc[nt][r] + bmc[nt]
                            + b2f(hs[(size_t)isv[r] * 128 + col]) + b2f(hd[(size_t)itv[r] * 128 + col]);
                    v = fmaxf(v, 0.f);
                    s1[nt] += v; s2[nt] += v * v;
                    if constexpr (STOREV)
                        vbuf[(size_t)(e0 + row16 + quad * 4 + r) * 128 + col] = f2b(v);
                }
            }
        } else {
            __syncthreads();
            #pragma unroll
            for (int nt = 0; nt < 4; nt++) {
                int col = colbase + nt * 16 + ln;
                #pragma unroll
                for (int r = 0; r < 4; r++) {
                    float v = uacc[nt][r] + bmc[nt]
                            + b2f(hs[(size_t)isv[r] * 128 + col]) + b2f(hd[(size_t)itv[r] * 128 + col]);
                    sT[row16 + quad * 4 + r][col] = f2b(fmaxf(v, 0.f));
                }
            }
            __syncthreads();
            f32x4 vacc[2] = {zero, zero};
            #pragma unroll
            for (int kk = 0; kk < 4; kk++) {
                bf16x8 aV = *(const bf16x8*)(&sT[row16 + ln][kk * 32 + quad * 8]);
                #pragma unroll
                for (int n2 = 0; n2 < 2; n2++) {
                    bf16x8 bV = *(const bf16x8*)(&sW2[32 * waveN + n2 * 16 + ln][kk * 32 + quad * 8]);
                    vacc[n2] = __builtin_amdgcn_mfma_f32_16x16x32_bf16(aV, bV, vacc[n2], 0, 0, 0);
                }
            }
            #pragma unroll
            for (int n2 = 0; n2 < 2; n2++) {
                int col2 = 32 * waveN + n2 * 16 + ln;
                #pragma unroll
                for (int r = 0; r < 4; r++)
                    sZ[row16 + quad * 4 + r][col2] = fmaxf(vacc[n2][r] + b2c[n2], 0.f);
            }
            __syncthreads();
            if (wave == 0) {
                int rw = lane & 31, half = lane >> 5;
                float o = 0.f;
                #pragma unroll 8
                for (int k2 = 0; k2 < 32; k2++)
                    o += sZ[rw][half * 32 + k2] * sW3[half * 32 + k2];
                o += __shfl_down(o, 32);
                if (lane < 32) outp[e0 + rw] = o + bm3v;
            }
        }
    }

    if (MODE < 2) {
        #pragma unroll
        for (int nt = 0; nt < 4; nt++) {
            float a1 = s1[nt], a2 = s2[nt];
            a1 += __shfl_down(a1, 32); a1 += __shfl_down(a1, 16);
            a2 += __shfl_down(a2, 32); a2 += __shfl_down(a2, 16);
            if (quad == 0) {
                atomicAdd(&sRed[0][colbase + nt * 16 + ln], a1);
                atomicAdd(&sRed[1][colbase + nt * 16 + ln], a2);
            }
        }
        __syncthreads();
        if (tid < 128) {
            atomicAdd(&ssum[tid], sRed[0][tid]);
            atomicAdd(&ssq[tid],  sRed[1][tid]);
        }
    }
}

extern "C" void kernel_launch(void* const* d_in, const int* in_sizes, int n_in,
                              void* d_out, int out_size, void* d_ws, size_t ws_size,
                              hipStream_t stream) {
    const float* x     = (const float*)d_in[0];
    const int*   ei    = (const int*)  d_in[1];
    const float* eattr = (const float*)d_in[2];
    const int*   esrc  = (const int*)  d_in[3];
    const int*   etgt  = (const int*)  d_in[4];
    const float* W1l = (const float*)d_in[5];  const float* b1 = (const float*)d_in[6];
    const float* W1r = (const float*)d_in[7];
    const float* W2l = (const float*)d_in[8];  const float* b2 = (const float*)d_in[9];
    const float* W2r = (const float*)d_in[10];
    const float* bn1_g = (const float*)d_in[11]; const float* bn1_b = (const float*)d_in[12];
    const float* bn2_g = (const float*)d_in[13]; const float* bn2_b = (const float*)d_in[14];
    const float* We  = (const float*)d_in[15]; const float* be  = (const float*)d_in[16];
    const float* bne_g = (const float*)d_in[17]; const float* bne_b = (const float*)d_in[18];
    const float* Wm1 = (const float*)d_in[19]; const float* bm1 = (const float*)d_in[20];
    const float* bnm_g = (const float*)d_in[21]; const float* bnm_b = (const float*)d_in[22];
    const float* Wm2 = (const float*)d_in[23]; const float* bm2 = (const float*)d_in[24];
    const float* Wm3 = (const float*)d_in[25]; const float* bm3 = (const float*)d_in[26];
    float* out = (float*)d_out;

    char* base = (char*)d_ws;
    size_t o = 0;
    auto A = [&](size_t bytes) { char* p = base + o; o = (o + bytes + 255) & ~(size_t)255; return p; };
    short* hsb   = (short*)A((size_t)NN * 128 * 2);
    short* hdb   = (short*)A((size_t)NN * 128 * 2);
    int*   deg   = (int*)  A((size_t)NN * 4);
    int*   rowptr= (int*)  A((size_t)(NN + 1) * 4);
    int*   wp    = (int*)  A((size_t)NN * 4);
    int*   elist = (int*)  A((size_t)NE * 4);
    float* st    = (float*)A(1024 * 4);
    float* sc1   = (float*)A(512); float* sh1 = (float*)A(512);
    float* sc2   = (float*)A(512); float* sh2 = (float*)A(512);
    float* bm1p  = (float*)A(512); float* b2p = (float*)A(256);
    short* WteT  = (short*)A(128 * 32 * 2);
    short* W1pT  = (short*)A(128 * 128 * 2);
    short* WmsT  = (short*)A(128 * 128 * 2);
    short* WmdT  = (short*)A(128 * 128 * 2);
    short* W2pT  = (short*)A(64 * 128 * 2);
    short* W2cT  = (short*)A(128 * 256 * 2);
    size_t chain = o;
    float* meanX = (float*)A((size_t)NN * 32 * 4);
    short* h1b   = (short*)A((size_t)NN * 128 * 2);
    short* m2b   = (short*)A((size_t)NN * 128 * 2);
    short* h2b   = (short*)A((size_t)NN * 128 * 2);
    short* vbuf  = (short*)(base + chain);              // aliases meanX..h2b (all dead by then)
    bool storev = ws_size >= chain + (size_t)NE * 128 * 2;

    hipMemsetAsync(deg, 0, (size_t)NN * 4, stream);
    hipMemsetAsync(st, 0, 1024 * 4, stream);

    // weight prep + CSR build
    k_prep<<<5, 128, 0, stream>>>(We, Wm1, W2l, W2r, WteT, WmsT, WmdT, W2cT);
    k_hist<<<(NE + 255) / 256, 256, 0, stream>>>(ei, deg);
    k_scan<<<1, 1024, 0, stream>>>(deg, rowptr, wp);
    k_scatter<<<(NE + 255) / 256, 256, 0, stream>>>(ei, wp, elist);

    // edge bne stats (only needs WteT)
    k_edge_mfma<0><<<1024, 256, 0, stream>>>(eattr, WteT, be, W1pT, bm1p, hsb, hdb,
        esrc, etgt, W2pT, b2p, Wm3, bm3, st + 512, st + 640, nullptr, out);
    k_fold_e<<<1, 128, 0, stream>>>(st + 512, st + 640, bne_g, bne_b, Wm1, bm1, W1pT, bm1p);

    // ---- layer 1 ----
    k_gagg1<<<NN / 8, 256, 0, stream>>>(x, rowptr, elist, meanX);
    k_node_l1<<<NN / 32, 256, 0, stream>>>(meanX, x, W1l, W1r, b1, h1b, st + 0, st + 128);
    k_bn_fin<<<1, 128, 0, stream>>>(st + 0, st + 128, bn1_g, bn1_b, (float)NN, sc1, sh1);

    // ---- layer 2 ----
    k_gagg2<<<NN / 2, 256, 0, stream>>>(h1b, rowptr, elist, sc1, sh1, m2b);
    k_node_l2m<<<640, 256, 0, stream>>>(m2b, h1b, sc1, sh1, W2cT, b2, h2b, st + 256, st + 384);
    k_bn_fin<<<1, 128, 0, stream>>>(st + 256, st + 384, bn2_g, bn2_b, (float)NN, sc2, sh2);

    // ---- node projections ----
    k_proj_mfma<<<640, 256, 0, stream>>>(h2b, sc2, sh2, WmsT, hsb);
    k_proj_mfma<<<640, 256, 0, stream>>>(h2b, sc2, sh2, WmdT, hdb);

    // ---- edge main ----
    if (storev)
        k_edge_mfma<1, true><<<1280, 256, 0, stream>>>(eattr, WteT, be, W1pT, bm1p, hsb, hdb,
            esrc, etgt, W2pT, b2p, Wm3, bm3, st + 768, st + 896, vbuf, out);
    else
        k_edge_mfma<1, false><<<1280, 256, 0, stream>>>(eattr, WteT, be, W1pT, bm1p, hsb, hdb,
            esrc, etgt, W2pT, b2p, Wm3, bm3, st + 768, st + 896, nullptr, out);
    k_fold_m<<<1, 128, 0, stream>>>(st + 768, st + 896, bnm_g, bnm_b, Wm2, bm2, W2pT, b2p);

    // ---- edge final ----
    if (storev)
        k_edge_mfma<3><<<2048, 256, 0, stream>>>(eattr, WteT, be, W1pT, bm1p, hsb, hdb,
            esrc, etgt, W2pT, b2p, Wm3, bm3, nullptr, nullptr, vbuf, out);
    else
        k_edge_mfma<2><<<1280, 256, 0, stream>>>(eattr, WteT, be, W1pT, bm1p, hsb, hdb,
            esrc, etgt, W2pT, b2p, Wm3, bm3, nullptr, nullptr, nullptr, out);
}

// Round 4
// 856.600 us; speedup vs baseline: 3.9302x; 1.3605x over previous
//
#include <hip/hip_runtime.h>
#include <hip/hip_bf16.h>

#define NN 100000
#define NE 800000
#define SCAN_NB 98   // ceil(NN / 1024)

typedef __attribute__((ext_vector_type(8))) short bf16x8;
typedef __attribute__((ext_vector_type(4))) float f32x4;

__device__ __forceinline__ short f2b(float f) {
    unsigned u = __float_as_uint(f);
    unsigned r = (u + 0x7fffu + ((u >> 16) & 1u)) >> 16;
    return (short)r;
}
__device__ __forceinline__ float b2f(short s) {
    return __uint_as_float(((unsigned)(unsigned short)s) << 16);
}

// ---------------- CSR build ----------------
__global__ __launch_bounds__(256) void k_hist(const int* __restrict__ ei, int* __restrict__ deg)
{
    int e = blockIdx.x * 256 + threadIdx.x;
    if (e < NE) atomicAdd(&deg[ei[NE + e]], 1);
}

// phase a: per-block exclusive scan (coalesced), block sums out
__global__ __launch_bounds__(1024) void k_scan_a(const int* __restrict__ deg,
    int* __restrict__ tmp, int* __restrict__ bsum)
{
    __shared__ int sh[1024];
    int t = threadIdx.x, b = blockIdx.x;
    int idx = b * 1024 + t;
    int v = (idx < NN) ? deg[idx] : 0;
    sh[t] = v;
    __syncthreads();
    for (int ofs = 1; ofs < 1024; ofs <<= 1) {
        int u = (t >= ofs) ? sh[t - ofs] : 0;
        __syncthreads();
        sh[t] += u;
        __syncthreads();
    }
    if (idx < NN) tmp[idx] = sh[t] - v;   // exclusive within block
    if (t == 1023) bsum[b] = sh[1023];
}

// phase b: scan 98 block sums (tiny)
__global__ void k_scan_b(const int* __restrict__ bsum, int* __restrict__ boff,
    int* __restrict__ rowptr)
{
    if (threadIdx.x == 0) {
        int acc = 0;
        for (int i = 0; i < SCAN_NB; i++) { boff[i] = acc; acc += bsum[i]; }
        rowptr[NN] = acc;
    }
}

// phase c: add block offset, write rowptr + wp
__global__ __launch_bounds__(1024) void k_scan_c(const int* __restrict__ tmp,
    const int* __restrict__ boff, int* __restrict__ rowptr, int* __restrict__ wp)
{
    int b = blockIdx.x, t = threadIdx.x;
    int idx = b * 1024 + t;
    if (idx < NN) {
        int v = boff[b] + tmp[idx];
        rowptr[idx] = v; wp[idx] = v;
    }
}

__global__ __launch_bounds__(256) void k_scatter(const int* __restrict__ ei,
    int* __restrict__ wp, int* __restrict__ elist)
{
    int e = blockIdx.x * 256 + threadIdx.x;
    if (e < NE) {
        int d = ei[NE + e];
        int pos = atomicAdd(&wp[d], 1);
        elist[pos] = ei[e];
    }
}

// ---------------- gather aggregation (no atomics) ----------------
__global__ __launch_bounds__(256) void k_gagg1(const float* __restrict__ x,
    const int* __restrict__ rowptr, const int* __restrict__ elist, float* __restrict__ meanX)
{
    int n = blockIdx.x * 8 + (threadIdx.x >> 5);
    int j = threadIdx.x & 31;
    int b = rowptr[n], e = rowptr[n + 1];
    float acc = 0.f;
    for (int i = b; i < e; i++) {
        int s = elist[i];
        acc += x[(size_t)s * 32 + j];
    }
    float inv = (e > b) ? 1.0f / (float)(e - b) : 1.0f;
    meanX[(size_t)n * 32 + j] = acc * inv;
}

// 8 nodes per block, 32 lanes per node, ushort4 (4 cols) per lane
__global__ __launch_bounds__(256) void k_gagg2(const short* __restrict__ h1b,
    const int* __restrict__ rowptr, const int* __restrict__ elist,
    const float* __restrict__ sc1, const float* __restrict__ sh1, short* __restrict__ m2b)
{
    int n = blockIdx.x * 8 + (threadIdx.x >> 5);
    int c0 = (threadIdx.x & 31) * 4;
    float sc[4], sh[4];
    #pragma unroll
    for (int i = 0; i < 4; i++) { sc[i] = sc1[c0 + i]; sh[i] = sh1[c0 + i]; }
    int b = rowptr[n], e = rowptr[n + 1];
    float acc[4] = {0.f, 0.f, 0.f, 0.f};
    for (int i = b; i < e; i++) {
        int s = elist[i];
        ushort4 u = *(const ushort4*)(h1b + (size_t)s * 128 + c0);
        acc[0] += fmaxf(b2f((short)u.x) * sc[0] + sh[0], 0.f);
        acc[1] += fmaxf(b2f((short)u.y) * sc[1] + sh[1], 0.f);
        acc[2] += fmaxf(b2f((short)u.z) * sc[2] + sh[2], 0.f);
        acc[3] += fmaxf(b2f((short)u.w) * sc[3] + sh[3], 0.f);
    }
    float inv = (e > b) ? 1.0f / (float)(e - b) : 1.0f;
    ushort4 o;
    o.x = (unsigned short)f2b(acc[0] * inv);
    o.y = (unsigned short)f2b(acc[1] * inv);
    o.z = (unsigned short)f2b(acc[2] * inv);
    o.w = (unsigned short)f2b(acc[3] * inv);
    *(ushort4*)(m2b + (size_t)n * 128 + c0) = o;
}

// ---------------- SAGE layer 1 (fp32 VALU, K=32+32), writes h1b bf16 + stats ----------------
__global__ __launch_bounds__(256) void k_node_l1(
    const float* __restrict__ meanX, const float* __restrict__ x,
    const float* __restrict__ Wl, const float* __restrict__ Wr,
    const float* __restrict__ bias,
    short* __restrict__ outp, float* __restrict__ ssum, float* __restrict__ ssq)
{
    __shared__ __align__(16) float sWl[32][128];
    __shared__ __align__(16) float sWr[32][128];
    __shared__ __align__(16) float sA[32][36];
    __shared__ __align__(16) float sB[32][36];
    __shared__ float red[2][128], red2[2][128];
    int tid = threadIdx.x;
    int j = tid & 127, rg = tid >> 7;
    int r0 = blockIdx.x * 32;

    for (int f = tid * 4; f < 4096; f += 1024) {
        *(float4*)((float*)sWl + f) = *(const float4*)(Wl + f);
        *(float4*)((float*)sWr + f) = *(const float4*)(Wr + f);
    }
    {
        int r = tid >> 3, c = (tid & 7) * 4;
        *(float4*)(&sA[r][c]) = *(const float4*)(meanX + (size_t)(r0 + r) * 32 + c);
        *(float4*)(&sB[r][c]) = *(const float4*)(x + (size_t)(r0 + r) * 32 + c);
    }
    __syncthreads();

    float acc[16];
    #pragma unroll
    for (int r = 0; r < 16; r++) acc[r] = 0.0f;
    int rb = rg * 16;
    #pragma unroll
    for (int kq = 0; kq < 8; kq++) {
        int k = kq * 4;
        float wl0 = sWl[k][j], wl1 = sWl[k+1][j], wl2 = sWl[k+2][j], wl3 = sWl[k+3][j];
        float wr0 = sWr[k][j], wr1 = sWr[k+1][j], wr2 = sWr[k+2][j], wr3 = sWr[k+3][j];
        #pragma unroll
        for (int r = 0; r < 16; r++) {
            float4 a = *(float4*)(&sA[rb + r][k]);
            float4 b = *(float4*)(&sB[rb + r][k]);
            acc[r] += a.x*wl0 + a.y*wl1 + a.z*wl2 + a.w*wl3
                    + b.x*wr0 + b.y*wr1 + b.z*wr2 + b.w*wr3;
        }
    }
    float bj = bias[j];
    float s1 = 0.0f, s2 = 0.0f;
    #pragma unroll
    for (int r = 0; r < 16; r++) {
        float v = acc[r] + bj;
        outp[(size_t)(r0 + rb + r) * 128 + j] = f2b(v);
        s1 += v; s2 += v * v;
    }
    red[rg][j] = s1; red2[rg][j] = s2;
    __syncthreads();
    if (rg == 0) {
        atomicAdd(&ssum[j], red[0][j] + red[1][j]);
        atomicAdd(&ssq[j],  red2[0][j] + red2[1][j]);
    }
}

// ---------------- SAGE layer 2 via MFMA: h2 = [mean | bnrelu(h1)] @ W2c + b2 ----------------
__global__ __launch_bounds__(256) void k_node_l2m(
    const short* __restrict__ m2b, const short* __restrict__ h1b,
    const float* __restrict__ sc1, const float* __restrict__ sh1,
    const short* __restrict__ W2cT, const float* __restrict__ bias,
    short* __restrict__ h2b, float* __restrict__ ssum, float* __restrict__ ssq)
{
    __shared__ __align__(16) short sK[32][264];
    __shared__ float sRed[2][128];
    __shared__ float sS[128], sH[128];
    const int tid = threadIdx.x;
    const int wave = tid >> 6, lane = tid & 63, quad = lane >> 4, ln = lane & 15;
    const int waveM = wave >> 1, waveN = wave & 1;
    const int colbase = 64 * waveN, row16 = 16 * waveM;
    if (tid < 128) { sS[tid] = sc1[tid]; sH[tid] = sh1[tid]; sRed[0][tid] = 0.f; sRed[1][tid] = 0.f; }

    bf16x8 bW[4][8];
    #pragma unroll
    for (int nt = 0; nt < 4; nt++)
        #pragma unroll
        for (int kk = 0; kk < 8; kk++)
            bW[nt][kk] = *(const bf16x8*)(W2cT + (size_t)(colbase + nt * 16 + ln) * 256 + kk * 32 + quad * 8);
    float bc[4];
    #pragma unroll
    for (int nt = 0; nt < 4; nt++) bc[nt] = bias[colbase + nt * 16 + ln];

    float s1[4] = {0,0,0,0}, s2[4] = {0,0,0,0};
    f32x4 zero = {0.f, 0.f, 0.f, 0.f};
    __syncthreads();

    for (int t = blockIdx.x; t < NN / 32; t += gridDim.x) {
        int r0 = t * 32;
        __syncthreads();
        {
            int r = tid >> 3, seg = tid & 7;
            if (seg < 4) {
                const bf16x8* src = (const bf16x8*)(m2b + (size_t)(r0 + r) * 128 + seg * 32);
                bf16x8* dst = (bf16x8*)(&sK[r][seg * 32]);
                dst[0] = src[0]; dst[1] = src[1]; dst[2] = src[2]; dst[3] = src[3];
            } else {
                int c0 = (seg - 4) * 32;
                const short* src = h1b + (size_t)(r0 + r) * 128 + c0;
                short tmp[32];
                #pragma unroll
                for (int i = 0; i < 32; i++)
                    tmp[i] = f2b(fmaxf(b2f(src[i]) * sS[c0 + i] + sH[c0 + i], 0.f));
                bf16x8* dst = (bf16x8*)(&sK[r][128 + c0]);
                dst[0] = *(bf16x8*)(tmp); dst[1] = *(bf16x8*)(tmp + 8);
                dst[2] = *(bf16x8*)(tmp + 16); dst[3] = *(bf16x8*)(tmp + 24);
            }
        }
        __syncthreads();
        f32x4 acc[4] = {zero, zero, zero, zero};
        #pragma unroll
        for (int kk = 0; kk < 8; kk++) {
            bf16x8 a = *(const bf16x8*)(&sK[row16 + ln][kk * 32 + quad * 8]);
            #pragma unroll
            for (int nt = 0; nt < 4; nt++)
                acc[nt] = __builtin_amdgcn_mfma_f32_16x16x32_bf16(a, bW[nt][kk], acc[nt], 0, 0, 0);
        }
        #pragma unroll
        for (int nt = 0; nt < 4; nt++) {
            int col = colbase + nt * 16 + ln;
            #pragma unroll
            for (int r = 0; r < 4; r++) {
                float v = acc[nt][r] + bc[nt];
                h2b[(size_t)(r0 + row16 + quad * 4 + r) * 128 + col] = f2b(v);
                s1[nt] += v; s2[nt] += v * v;
            }
        }
    }
    #pragma unroll
    for (int nt = 0; nt < 4; nt++) {
        float a1 = s1[nt], a2 = s2[nt];
        a1 += __shfl_down(a1, 32); a1 += __shfl_down(a1, 16);
        a2 += __shfl_down(a2, 32); a2 += __shfl_down(a2, 16);
        if (quad == 0) {
            atomicAdd(&sRed[0][colbase + nt * 16 + ln], a1);
            atomicAdd(&sRed[1][colbase + nt * 16 + ln], a2);
        }
    }
    __syncthreads();
    if (tid < 128) {
        atomicAdd(&ssum[tid], sRed[0][tid]);
        atomicAdd(&ssq[tid],  sRed[1][tid]);
    }
}

// ---------------- batch-norm finalize ----------------
__global__ void k_bn_fin(const float* __restrict__ ssum, const float* __restrict__ ssq,
    const float* __restrict__ g, const float* __restrict__ b, float count,
    float* __restrict__ scale, float* __restrict__ shift)
{
    int j = threadIdx.x;
    float m = ssum[j] / count;
    float var = ssq[j] / count - m * m;
    float rs = rsqrtf(var + 1e-5f);
    float sc = g[j] * rs;
    scale[j] = sc;
    shift[j] = b[j] - m * sc;
}

// ---------------- prep: transposed bf16 weights ----------------
__global__ void k_prep(const float* __restrict__ We, const float* __restrict__ Wm1,
                       const float* __restrict__ W2l, const float* __restrict__ W2r,
                       short* __restrict__ WteT, short* __restrict__ WmsT,
                       short* __restrict__ WmdT, short* __restrict__ W2cT)
{
    int j = threadIdx.x;  // 128
    int b = blockIdx.x;
    if (b == 0) {
        for (int k = 0; k < 32; k++)
            WteT[j * 32 + k] = (k < 16) ? f2b(We[k * 128 + j]) : (short)0;
    } else if (b == 1) {
        for (int k = 0; k < 128; k++) WmsT[j * 128 + k] = f2b(Wm1[k * 128 + j]);
    } else if (b == 2) {
        for (int k = 0; k < 128; k++) WmdT[j * 128 + k] = f2b(Wm1[(128 + k) * 128 + j]);
    } else if (b == 3) {
        for (int k = 0; k < 128; k++) W2cT[j * 256 + k] = f2b(W2l[k * 128 + j]);
    } else {
        for (int k = 0; k < 128; k++) W2cT[j * 256 + 128 + k] = f2b(W2r[k * 128 + j]);
    }
}

// ---------------- fold bne into Wm1[256:384] -> W1pT ----------------
__global__ void k_fold_e(const float* __restrict__ ssum, const float* __restrict__ ssq,
    const float* __restrict__ g, const float* __restrict__ b,
    const float* __restrict__ Wm1, const float* __restrict__ bm1,
    short* __restrict__ W1pT, float* __restrict__ bm1p)
{
    __shared__ float sa[128], sc[128];
    int tid = threadIdx.x;
    float m = ssum[tid] / (float)NE;
    float var = ssq[tid] / (float)NE - m * m;
    float rs = rsqrtf(var + 1e-5f);
    float a = g[tid] * rs;
    sa[tid] = a; sc[tid] = b[tid] - m * a;
    __syncthreads();
    float acc = bm1[tid];
    for (int k = 0; k < 128; k++) {
        float w = Wm1[(256 + k) * 128 + tid];
        W1pT[tid * 128 + k] = f2b(sa[k] * w);
        acc += sc[k] * w;
    }
    bm1p[tid] = acc;
}

// ---------------- fold bnm into Wm2 -> W2pT ----------------
__global__ void k_fold_m(const float* __restrict__ ssum, const float* __restrict__ ssq,
    const float* __restrict__ g, const float* __restrict__ b,
    const float* __restrict__ Wm2, const float* __restrict__ bm2,
    short* __restrict__ W2pT, float* __restrict__ b2p)
{
    __shared__ float sa[128], sc[128];
    int tid = threadIdx.x;
    float m = ssum[tid] / (float)NE;
    float var = ssq[tid] / (float)NE - m * m;
    float rs = rsqrtf(var + 1e-5f);
    float a = g[tid] * rs;
    sa[tid] = a; sc[tid] = b[tid] - m * a;
    __syncthreads();
    if (tid < 64) {
        float acc = bm2[tid];
        for (int k = 0; k < 128; k++) {
            float w = Wm2[k * 64 + tid];
            W2pT[tid * 128 + k] = f2b(sa[k] * w);
            acc += sc[k] * w;
        }
        b2p[tid] = acc;
    }
}

// ---------------- node projection: C(bf16) = bnrelu(h2b) @ W via MFMA ----------------
__global__ __launch_bounds__(256) void k_proj_mfma(
    const short* __restrict__ h2b, const float* __restrict__ sc2, const float* __restrict__ sh2,
    const short* __restrict__ WT, short* __restrict__ C)
{
    __shared__ __align__(16) short sA[32][136];
    __shared__ float sS[128], sH[128];
    const int tid = threadIdx.x;
    const int wave = tid >> 6, lane = tid & 63, quad = lane >> 4, ln = lane & 15;
    const int waveM = wave >> 1, waveN = wave & 1;
    const int colbase = 64 * waveN, row16 = 16 * waveM;
    if (tid < 128) { sS[tid] = sc2[tid]; sH[tid] = sh2[tid]; }
    bf16x8 bW[4][4];
    #pragma unroll
    for (int nt = 0; nt < 4; nt++)
        #pragma unroll
        for (int kk = 0; kk < 4; kk++)
            bW[nt][kk] = *(const bf16x8*)(WT + (colbase + nt * 16 + ln) * 128 + kk * 32 + quad * 8);
    f32x4 zero = {0.f, 0.f, 0.f, 0.f};
    __syncthreads();
    for (int t = blockIdx.x; t < NN / 32; t += gridDim.x) {
        int r0 = t * 32;
        __syncthreads();
        {
            int r = tid >> 3, c0 = (tid & 7) * 16;
            const short* p = h2b + (size_t)(r0 + r) * 128 + c0;
            short tmp[16];
            #pragma unroll
            for (int i = 0; i < 16; i++)
                tmp[i] = f2b(fmaxf(b2f(p[i]) * sS[c0 + i] + sH[c0 + i], 0.f));
            *(bf16x8*)(&sA[r][c0])     = *(bf16x8*)tmp;
            *(bf16x8*)(&sA[r][c0 + 8]) = *(bf16x8*)(tmp + 8);
        }
        __syncthreads();
        f32x4 acc[4] = {zero, zero, zero, zero};
        #pragma unroll
        for (int kk = 0; kk < 4; kk++) {
            bf16x8 a = *(const bf16x8*)(&sA[row16 + ln][kk * 32 + quad * 8]);
            #pragma unroll
            for (int nt = 0; nt < 4; nt++)
                acc[nt] = __builtin_amdgcn_mfma_f32_16x16x32_bf16(a, bW[nt][kk], acc[nt], 0, 0, 0);
        }
        #pragma unroll
        for (int nt = 0; nt < 4; nt++) {
            int col = colbase + nt * 16 + ln;
            #pragma unroll
            for (int r = 0; r < 4; r++)
                C[(size_t)(r0 + row16 + quad * 4 + r) * 128 + col] = f2b(acc[nt][r]);
        }
    }
}

// ---------------- edge pipeline via MFMA ----------------
// MODE 0: bne stats of t = relu(ea@We+be)
// MODE 1: v = relu(t@W1p + bm1p + hs[es] + hd[et]); bnm stats; optional store v (bf16)
// MODE 2: recompute v; z2 = relu(v@W2p + b2p); out = z2@Wm3 + bm3
// MODE 3: load v from vbuf; z2/out as MODE 2
template<int MODE, bool STOREV = false>
__global__ __launch_bounds__(256) void k_edge_mfma(
    const float* __restrict__ ea,
    const short* __restrict__ WteT, const float* __restrict__ be,
    const short* __restrict__ W1pT, const float* __restrict__ bm1p,
    const short* __restrict__ hs, const short* __restrict__ hd,
    const int* __restrict__ esrc, const int* __restrict__ etgt,
    const short* __restrict__ W2pT, const float* __restrict__ b2p,
    const float* __restrict__ Wm3, const float* __restrict__ bm3,
    float* __restrict__ ssum, float* __restrict__ ssq,
    short* __restrict__ vbuf, float* __restrict__ outp)
{
    __shared__ __align__(16) short sT[32][136];
    __shared__ float sRed[2][128];
    __shared__ __align__(16) short sW2[64][136];
    __shared__ float sZ[32][69];
    __shared__ float sW3[64];

    const int tid = threadIdx.x;
    const int wave = tid >> 6, lane = tid & 63;
    const int quad = lane >> 4, ln = lane & 15;
    const int waveM = wave >> 1, waveN = wave & 1;
    const int colbase = 64 * waveN, row16 = 16 * waveM;

    if (MODE < 2) {
        if (tid < 128) { sRed[0][tid] = 0.f; sRed[1][tid] = 0.f; }
    }
    if (MODE >= 2) {
        int q = tid >> 2, kb = (tid & 3) * 32;
        const bf16x8* src = (const bf16x8*)(W2pT + q * 128 + kb);
        bf16x8* dst = (bf16x8*)(&sW2[q][kb]);
        dst[0] = src[0]; dst[1] = src[1]; dst[2] = src[2]; dst[3] = src[3];
        if (tid < 64) sW3[tid] = Wm3[tid];
    }

    bf16x8 bWe[4], bW1[4][4];
    if (MODE <= 2) {
        #pragma unroll
        for (int nt = 0; nt < 4; nt++) {
            bWe[nt] = *(const bf16x8*)(WteT + (colbase + nt * 16 + ln) * 32 + quad * 8);
            if (MODE >= 1) {
                #pragma unroll
                for (int kk = 0; kk < 4; kk++)
                    bW1[nt][kk] = *(const bf16x8*)(W1pT + (colbase + nt * 16 + ln) * 128 + kk * 32 + quad * 8);
            }
        }
    }
    float bec[4], bmc[4];
    #pragma unroll
    for (int nt = 0; nt < 4; nt++) {
        bec[nt] = (MODE <= 2) ? be[colbase + nt * 16 + ln] : 0.f;
        bmc[nt] = (MODE == 1 || MODE == 2) ? bm1p[colbase + nt * 16 + ln] : 0.f;
    }
    float b2c[2] = {0.f, 0.f};
    if (MODE >= 2) { b2c[0] = b2p[32 * waveN + ln]; b2c[1] = b2p[32 * waveN + 16 + ln]; }
    float bm3v = (MODE >= 2) ? bm3[0] : 0.f;

    float s1[4] = {0,0,0,0}, s2[4] = {0,0,0,0};
    f32x4 zero = {0.f, 0.f, 0.f, 0.f};
    __syncthreads();

    for (int t = blockIdx.x; t < NE / 32; t += gridDim.x) {
        const int e0 = t * 32;

        if (MODE == 3) {
            f32x4 vacc[2] = {zero, zero};
            #pragma unroll
            for (int kk = 0; kk < 4; kk++) {
                bf16x8 aV = *(const bf16x8*)(vbuf + (size_t)(e0 + row16 + ln) * 128 + kk * 32 + quad * 8);
                #pragma unroll
                for (int n2 = 0; n2 < 2; n2++) {
                    bf16x8 bV = *(const bf16x8*)(&sW2[32 * waveN + n2 * 16 + ln][kk * 32 + quad * 8]);
                    vacc[n2] = __builtin_amdgcn_mfma_f32_16x16x32_bf16(aV, bV, vacc[n2], 0, 0, 0);
                }
            }
            __syncthreads();
            #pragma unroll
            for (int n2 = 0; n2 < 2; n2++) {
                int col2 = 32 * waveN + n2 * 16 + ln;
                #pragma unroll
                for (int r = 0; r < 4; r++)
                    sZ[row16 + quad * 4 + r][col2] = fmaxf(vacc[n2][r] + b2c[n2], 0.f);
            }
            __syncthreads();
            if (wave == 0) {
                int rw = lane & 31, half = lane >> 5;
                float o = 0.f;
                #pragma unroll 8
                for (int k2 = 0; k2 < 32; k2++)
                    o += sZ[rw][half * 32 + k2] * sW3[half * 32 + k2];
                o += __shfl_down(o, 32);
                if (lane < 32) outp[e0 + rw] = o + bm3v;
            }
            continue;
        }

        // ---- t-GEMM (K padded to 32) ----
        bf16x8 aE;
        #pragma unroll
        for (int i = 0; i < 8; i++) aE[i] = 0;
        if (quad < 2) {
            const float* p = ea + (size_t)(e0 + row16 + ln) * 16 + quad * 8;
            float4 f0 = *(const float4*)p, f1 = *(const float4*)(p + 4);
            aE[0]=f2b(f0.x); aE[1]=f2b(f0.y); aE[2]=f2b(f0.z); aE[3]=f2b(f0.w);
            aE[4]=f2b(f1.x); aE[5]=f2b(f1.y); aE[6]=f2b(f1.z); aE[7]=f2b(f1.w);
        }
        f32x4 tacc[4];
        #pragma unroll
        for (int nt = 0; nt < 4; nt++)
            tacc[nt] = __builtin_amdgcn_mfma_f32_16x16x32_bf16(aE, bWe[nt], zero, 0, 0, 0);

        if (MODE == 0) {
            #pragma unroll
            for (int nt = 0; nt < 4; nt++)
                #pragma unroll
                for (int r = 0; r < 4; r++) {
                    float v = fmaxf(tacc[nt][r] + bec[nt], 0.f);
                    s1[nt] += v; s2[nt] += v * v;
                }
            continue;
        }

        __syncthreads();
        #pragma unroll
        for (int nt = 0; nt < 4; nt++) {
            int col = colbase + nt * 16 + ln;
            #pragma unroll
            for (int r = 0; r < 4; r++)
                sT[row16 + quad * 4 + r][col] = f2b(fmaxf(tacc[nt][r] + bec[nt], 0.f));
        }
        __syncthreads();

        // ---- u-GEMM ----
        f32x4 uacc[4] = {zero, zero, zero, zero};
        #pragma unroll
        for (int kk = 0; kk < 4; kk++) {
            bf16x8 aU = *(const bf16x8*)(&sT[row16 + ln][kk * 32 + quad * 8]);
            #pragma unroll
            for (int nt = 0; nt < 4; nt++)
                uacc[nt] = __builtin_amdgcn_mfma_f32_16x16x32_bf16(aU, bW1[nt][kk], uacc[nt], 0, 0, 0);
        }

        int4 is4 = *(const int4*)(esrc + e0 + row16 + quad * 4);
        int4 it4 = *(const int4*)(etgt + e0 + row16 + quad * 4);
        int isv[4] = {is4.x, is4.y, is4.z, is4.w};
        int itv[4] = {it4.x, it4.y, it4.z, it4.w};

        if (MODE == 1) {
            #pragma unroll
            for (int nt = 0; nt < 4; nt++) {
                int col = colbase + nt * 16 + ln;
                #pragma unroll
                for (int r = 0; r < 4; r++) {
                    float v = uacc[nt][r] + bmc[nt]
                            + b2f(hs[(size_t)isv[r] * 128 + col]) + b2f(hd[(size_t)itv[r] * 128 + col]);
                    v = fmaxf(v, 0.f);
                    s1[nt] += v; s2[nt] += v * v;
                    if constexpr (STOREV)
                        vbuf[(size_t)(e0 + row16 + quad * 4 + r) * 128 + col] = f2b(v);
                }
            }
        } else {
            __syncthreads();
            #pragma unroll
            for (int nt = 0; nt < 4; nt++) {
                int col = colbase + nt * 16 + ln;
                #pragma unroll
                for (int r = 0; r < 4; r++) {
                    float v = uacc[nt][r] + bmc[nt]
                            + b2f(hs[(size_t)isv[r] * 128 + col]) + b2f(hd[(size_t)itv[r] * 128 + col]);
                    sT[row16 + quad * 4 + r][col] = f2b(fmaxf(v, 0.f));
                }
            }
            __syncthreads();
            f32x4 vacc[2] = {zero, zero};
            #pragma unroll
            for (int kk = 0; kk < 4; kk++) {
                bf16x8 aV = *(const bf16x8*)(&sT[row16 + ln][kk * 32 + quad * 8]);
                #pragma unroll
                for (int n2 = 0; n2 < 2; n2++) {
                    bf16x8 bV = *(const bf16x8*)(&sW2[32 * waveN + n2 * 16 + ln][kk * 32 + quad * 8]);
                    vacc[n2] = __builtin_amdgcn_mfma_f32_16x16x32_bf16(aV, bV, vacc[n2], 0, 0, 0);
                }
            }
            #pragma unroll
            for (int n2 = 0; n2 < 2; n2++) {
                int col2 = 32 * waveN + n2 * 16 + ln;
                #pragma unroll
                for (int r = 0; r < 4; r++)
                    sZ[row16 + quad * 4 + r][col2] = fmaxf(vacc[n2][r] + b2c[n2], 0.f);
            }
            __syncthreads();
            if (wave == 0) {
                int rw = lane & 31, half = lane >> 5;
                float o = 0.f;
                #pragma unroll 8
                for (int k2 = 0; k2 < 32; k2++)
                    o += sZ[rw][half * 32 + k2] * sW3[half * 32 + k2];
                o += __shfl_down(o, 32);
                if (lane < 32) outp[e0 + rw] = o + bm3v;
            }
        }
    }

    if (MODE < 2) {
        #pragma unroll
        for (int nt = 0; nt < 4; nt++) {
            float a1 = s1[nt], a2 = s2[nt];
            a1 += __shfl_down(a1, 32); a1 += __shfl_down(a1, 16);
            a2 += __shfl_down(a2, 32); a2 += __shfl_down(a2, 16);
            if (quad == 0) {
                atomicAdd(&sRed[0][colbase + nt * 16 + ln], a1);
                atomicAdd(&sRed[1][colbase + nt * 16 + ln], a2);
            }
        }
        __syncthreads();
        if (tid < 128) {
            atomicAdd(&ssum[tid], sRed[0][tid]);
            atomicAdd(&ssq[tid],  sRed[1][tid]);
        }
    }
}

extern "C" void kernel_launch(void* const* d_in, const int* in_sizes, int n_in,
                              void* d_out, int out_size, void* d_ws, size_t ws_size,
                              hipStream_t stream) {
    const float* x     = (const float*)d_in[0];
    const int*   ei    = (const int*)  d_in[1];
    const float* eattr = (const float*)d_in[2];
    const int*   esrc  = (const int*)  d_in[3];
    const int*   etgt  = (const int*)  d_in[4];
    const float* W1l = (const float*)d_in[5];  const float* b1 = (const float*)d_in[6];
    const float* W1r = (const float*)d_in[7];
    const float* W2l = (const float*)d_in[8];  const float* b2 = (const float*)d_in[9];
    const float* W2r = (const float*)d_in[10];
    const float* bn1_g = (const float*)d_in[11]; const float* bn1_b = (const float*)d_in[12];
    const float* bn2_g = (const float*)d_in[13]; const float* bn2_b = (const float*)d_in[14];
    const float* We  = (const float*)d_in[15]; const float* be  = (const float*)d_in[16];
    const float* bne_g = (const float*)d_in[17]; const float* bne_b = (const float*)d_in[18];
    const float* Wm1 = (const float*)d_in[19]; const float* bm1 = (const float*)d_in[20];
    const float* bnm_g = (const float*)d_in[21]; const float* bnm_b = (const float*)d_in[22];
    const float* Wm2 = (const float*)d_in[23]; const float* bm2 = (const float*)d_in[24];
    const float* Wm3 = (const float*)d_in[25]; const float* bm3 = (const float*)d_in[26];
    float* out = (float*)d_out;

    char* base = (char*)d_ws;
    size_t o = 0;
    auto A = [&](size_t bytes) { char* p = base + o; o = (o + bytes + 255) & ~(size_t)255; return p; };
    short* hsb   = (short*)A((size_t)NN * 128 * 2);
    short* hdb   = (short*)A((size_t)NN * 128 * 2);
    int*   deg   = (int*)  A((size_t)NN * 4);
    int*   rowptr= (int*)  A((size_t)(NN + 1) * 4);
    int*   wp    = (int*)  A((size_t)NN * 4);
    int*   elist = (int*)  A((size_t)NE * 4);
    float* st    = (float*)A(1024 * 4);
    int*   bsum  = (int*)  A(SCAN_NB * 4);
    int*   boff  = (int*)  A(SCAN_NB * 4);
    float* sc1   = (float*)A(512); float* sh1 = (float*)A(512);
    float* sc2   = (float*)A(512); float* sh2 = (float*)A(512);
    float* bm1p  = (float*)A(512); float* b2p = (float*)A(256);
    short* WteT  = (short*)A(128 * 32 * 2);
    short* W1pT  = (short*)A(128 * 128 * 2);
    short* WmsT  = (short*)A(128 * 128 * 2);
    short* WmdT  = (short*)A(128 * 128 * 2);
    short* W2pT  = (short*)A(64 * 128 * 2);
    short* W2cT  = (short*)A(128 * 256 * 2);
    size_t chain = o;
    float* meanX = (float*)A((size_t)NN * 32 * 4);
    short* h1b   = (short*)A((size_t)NN * 128 * 2);
    short* m2b   = (short*)A((size_t)NN * 128 * 2);
    short* h2b   = (short*)A((size_t)NN * 128 * 2);
    int*   stmp  = (int*)meanX;                         // scan tmp aliases meanX (dead until gagg1)
    short* vbuf  = (short*)(base + chain);              // aliases meanX..h2b (all dead by then)
    bool storev = ws_size >= chain + (size_t)NE * 128 * 2;

    hipMemsetAsync(deg, 0, (size_t)NN * 4, stream);
    hipMemsetAsync(st, 0, 1024 * 4, stream);

    // weight prep + CSR build (parallel 3-phase scan)
    k_prep<<<5, 128, 0, stream>>>(We, Wm1, W2l, W2r, WteT, WmsT, WmdT, W2cT);
    k_hist<<<(NE + 255) / 256, 256, 0, stream>>>(ei, deg);
    k_scan_a<<<SCAN_NB, 1024, 0, stream>>>(deg, stmp, bsum);
    k_scan_b<<<1, 64, 0, stream>>>(bsum, boff, rowptr);
    k_scan_c<<<SCAN_NB, 1024, 0, stream>>>(stmp, boff, rowptr, wp);
    k_scatter<<<(NE + 255) / 256, 256, 0, stream>>>(ei, wp, elist);

    // edge bne stats (only needs WteT)
    k_edge_mfma<0><<<1024, 256, 0, stream>>>(eattr, WteT, be, W1pT, bm1p, hsb, hdb,
        esrc, etgt, W2pT, b2p, Wm3, bm3, st + 512, st + 640, nullptr, out);
    k_fold_e<<<1, 128, 0, stream>>>(st + 512, st + 640, bne_g, bne_b, Wm1, bm1, W1pT, bm1p);

    // ---- layer 1 ----
    k_gagg1<<<NN / 8, 256, 0, stream>>>(x, rowptr, elist, meanX);
    k_node_l1<<<NN / 32, 256, 0, stream>>>(meanX, x, W1l, W1r, b1, h1b, st + 0, st + 128);
    k_bn_fin<<<1, 128, 0, stream>>>(st + 0, st + 128, bn1_g, bn1_b, (float)NN, sc1, sh1);

    // ---- layer 2 ----
    k_gagg2<<<NN / 8, 256, 0, stream>>>(h1b, rowptr, elist, sc1, sh1, m2b);
    k_node_l2m<<<640, 256, 0, stream>>>(m2b, h1b, sc1, sh1, W2cT, b2, h2b, st + 256, st + 384);
    k_bn_fin<<<1, 128, 0, stream>>>(st + 256, st + 384, bn2_g, bn2_b, (float)NN, sc2, sh2);

    // ---- node projections ----
    k_proj_mfma<<<640, 256, 0, stream>>>(h2b, sc2, sh2, WmsT, hsb);
    k_proj_mfma<<<640, 256, 0, stream>>>(h2b, sc2, sh2, WmdT, hdb);

    // ---- edge main ----
    if (storev)
        k_edge_mfma<1, true><<<1280, 256, 0, stream>>>(eattr, WteT, be, W1pT, bm1p, hsb, hdb,
            esrc, etgt, W2pT, b2p, Wm3, bm3, st + 768, st + 896, vbuf, out);
    else
        k_edge_mfma<1, false><<<1280, 256, 0, stream>>>(eattr, WteT, be, W1pT, bm1p, hsb, hdb,
            esrc, etgt, W2pT, b2p, Wm3, bm3, st + 768, st + 896, nullptr, out);
    k_fold_m<<<1, 128, 0, stream>>>(st + 768, st + 896, bnm_g, bnm_b, Wm2, bm2, W2pT, b2p);

    // ---- edge final ----
    if (storev)
        k_edge_mfma<3><<<2048, 256, 0, stream>>>(eattr, WteT, be, W1pT, bm1p, hsb, hdb,
            esrc, etgt, W2pT, b2p, Wm3, bm3, nullptr, nullptr, vbuf, out);
    else
        k_edge_mfma<2><<<1280, 256, 0, stream>>>(eattr, WteT, be, W1pT, bm1p, hsb, hdb,
            esrc, etgt, W2pT, b2p, Wm3, bm3, nullptr, nullptr, nullptr, out);
}